// Round 1
// baseline (800.646 us; speedup 1.0000x reference)
//
#include <hip/hip_runtime.h>
#include <hip/hip_bf16.h>
#include <math.h>

#define N_NODES 80000
#define N_EDGES 1280000
#define IN_C 128
#define HID_C 64
#define OUT_C 40

// ---------------- GEMM1: h1 = x @ W1  [80000x128 @ 128x64] ----------------
// Block: 256 threads = 4 rows x 64 cols. W1 (32 KB) staged in LDS.
__global__ void gemm1_kernel(const float* __restrict__ x,
                             const float* __restrict__ W1,
                             float* __restrict__ h1) {
    __shared__ float w[IN_C * HID_C];  // 32 KB
    for (int i = threadIdx.x; i < IN_C * HID_C; i += blockDim.x)
        w[i] = W1[i];
    __syncthreads();

    const int row = blockIdx.x * 4 + (threadIdx.x >> 6);   // wave-uniform
    const int col = threadIdx.x & 63;
    if (row >= N_NODES) return;

    const float* __restrict__ xr = x + (size_t)row * IN_C;
    float acc = 0.f;
#pragma unroll 8
    for (int k = 0; k < IN_C; ++k)
        acc += xr[k] * w[k * HID_C + col];
    h1[(size_t)row * HID_C + col] = acc;
}

// ---------------- SpMM1: agg1[dst] += h1[src]  (64 channels) ----------------
// Flat (edge, channel) parallelism: one thread per (e, c); wave = one edge's 64 ch.
__global__ void spmm1_kernel(const int* __restrict__ src,
                             const int* __restrict__ dst,
                             const float* __restrict__ h1,
                             float* __restrict__ agg1) {
    const long long idx = (long long)blockIdx.x * blockDim.x + threadIdx.x;
    const int e = (int)(idx >> 6);
    const int c = (int)(idx & 63);
    if (e >= N_EDGES) return;
    const int s = src[e];
    const int d = dst[e];
    atomicAdd(&agg1[(size_t)d * HID_C + c], h1[(size_t)s * HID_C + c]);
}

// ---------------- GEMM2: h2 = relu(agg1) @ W2  [80000x64 @ 64x40] ----------------
// One thread per output element; W2 (10 KB) in LDS. relu fused on the read.
__global__ void gemm2_kernel(const float* __restrict__ agg1,
                             const float* __restrict__ W2,
                             float* __restrict__ h2) {
    __shared__ float w[HID_C * OUT_C];  // 10 KB
    for (int i = threadIdx.x; i < HID_C * OUT_C; i += blockDim.x)
        w[i] = W2[i];
    __syncthreads();

    const long long idx = (long long)blockIdx.x * blockDim.x + threadIdx.x;
    if (idx >= (long long)N_NODES * OUT_C) return;
    const int row = (int)(idx / OUT_C);
    const int col = (int)(idx % OUT_C);

    const float* __restrict__ ar = agg1 + (size_t)row * HID_C;
    float acc = 0.f;
#pragma unroll 8
    for (int k = 0; k < HID_C; ++k) {
        float v = ar[k];
        v = v > 0.f ? v : 0.f;
        acc += v * w[k * OUT_C + col];
    }
    h2[idx] = acc;
}

// ---------------- SpMM2: out[dst] += h2[src]  (40 channels) ----------------
__global__ void spmm2_kernel(const int* __restrict__ src,
                             const int* __restrict__ dst,
                             const float* __restrict__ h2,
                             float* __restrict__ out) {
    const long long idx = (long long)blockIdx.x * blockDim.x + threadIdx.x;
    if (idx >= (long long)N_EDGES * OUT_C) return;
    const int e = (int)(idx / OUT_C);
    const int c = (int)(idx % OUT_C);
    const int s = src[e];
    const int d = dst[e];
    atomicAdd(&out[(size_t)d * OUT_C + c], h2[(size_t)s * OUT_C + c]);
}

// ---------------- log_softmax in-place over rows of 40 ----------------
// One wave (64 lanes) per row; lanes >= 40 idle in the math but join reductions.
__global__ void logsoftmax_kernel(float* __restrict__ io) {
    const int row = blockIdx.x * 4 + (threadIdx.x >> 6);
    const int lane = threadIdx.x & 63;
    if (row >= N_NODES) return;

    float v = (lane < OUT_C) ? io[(size_t)row * OUT_C + lane] : -INFINITY;

    float m = v;
#pragma unroll
    for (int o = 32; o > 0; o >>= 1)
        m = fmaxf(m, __shfl_down(m, o, 64));
    m = __shfl(m, 0, 64);

    float ex = (lane < OUT_C) ? __expf(v - m) : 0.f;
    float s = ex;
#pragma unroll
    for (int o = 32; o > 0; o >>= 1)
        s += __shfl_down(s, o, 64);
    s = __shfl(s, 0, 64);

    const float ls = __logf(s);
    if (lane < OUT_C)
        io[(size_t)row * OUT_C + lane] = v - m - ls;
}

extern "C" void kernel_launch(void* const* d_in, const int* in_sizes, int n_in,
                              void* d_out, int out_size, void* d_ws, size_t ws_size,
                              hipStream_t stream) {
    const float* x  = (const float*)d_in[0];
    const int* eidx = (const int*)d_in[1];
    const float* W1 = (const float*)d_in[2];
    const float* W2 = (const float*)d_in[3];
    float* out = (float*)d_out;

    const int* src = eidx;             // edge_index[0]
    const int* dst = eidx + N_EDGES;   // edge_index[1]

    // Workspace layout:
    //   bufA: h1 [80000*64 f32] (20.48 MB), later reused as h2 [80000*40 f32]
    //   bufB: agg1 [80000*64 f32] (20.48 MB)
    float* h1   = (float*)d_ws;
    float* agg1 = h1 + (size_t)N_NODES * HID_C;
    float* h2   = h1;  // h1 dead after spmm1

    // Zero accumulation targets (ws/out are poisoned with 0xAA each call).
    hipMemsetAsync(agg1, 0, (size_t)N_NODES * HID_C * sizeof(float), stream);
    hipMemsetAsync(out,  0, (size_t)N_NODES * OUT_C * sizeof(float), stream);

    // GEMM1
    gemm1_kernel<<<(N_NODES + 3) / 4, 256, 0, stream>>>(x, W1, h1);

    // SpMM1 (atomic scatter-add, 64 ch)
    {
        const long long total = (long long)N_EDGES * 64;
        const int blocks = (int)((total + 255) / 256);
        spmm1_kernel<<<blocks, 256, 0, stream>>>(src, dst, h1, agg1);
    }

    // GEMM2 (relu fused on read)
    {
        const long long total = (long long)N_NODES * OUT_C;
        const int blocks = (int)((total + 255) / 256);
        gemm2_kernel<<<blocks, 256, 0, stream>>>(agg1, W2, h2);
    }

    // SpMM2 (atomic scatter-add, 40 ch) into d_out
    {
        const long long total = (long long)N_EDGES * OUT_C;
        const int blocks = (int)((total + 255) / 256);
        spmm2_kernel<<<blocks, 256, 0, stream>>>(src, dst, h2, out);
    }

    // log_softmax in-place on d_out
    logsoftmax_kernel<<<(N_NODES + 3) / 4, 256, 0, stream>>>(out);
}

// Round 2
// 458.691 us; speedup vs baseline: 1.7455x; 1.7455x over previous
//
#include <hip/hip_runtime.h>
#include <hip/hip_bf16.h>
#include <math.h>

#define N_NODES 80000
#define N_EDGES 1280000
#define IN_C 128
#define HID_C 64
#define OUT_C 40

// ================= CSR build (by dst) =================
__global__ void hist_kernel(const int* __restrict__ dst, int* __restrict__ cnt) {
    const int e = blockIdx.x * 256 + threadIdx.x;
    if (e < N_EDGES) atomicAdd(&cnt[dst[e]], 1);
}

// Inclusive scan within 256-blocks; block totals to sums[].
__global__ void scan1_kernel(const int* __restrict__ cnt,
                             int* __restrict__ incl, int* __restrict__ sums) {
    __shared__ int tmp[256];
    const int gid = blockIdx.x * 256 + threadIdx.x;
    int v = (gid < N_NODES) ? cnt[gid] : 0;
    tmp[threadIdx.x] = v;
    __syncthreads();
    for (int o = 1; o < 256; o <<= 1) {
        int t = (threadIdx.x >= o) ? tmp[threadIdx.x - o] : 0;
        __syncthreads();
        tmp[threadIdx.x] += t;
        __syncthreads();
    }
    if (gid < N_NODES) incl[gid] = tmp[threadIdx.x];
    if (threadIdx.x == 255) sums[blockIdx.x] = tmp[255];
}

// Exclusive scan of block sums (single wave loops over chunks of 64).
__global__ void scan2_kernel(const int* __restrict__ sums, int* __restrict__ offs,
                             int nblocks) {
    const int lane = threadIdx.x;
    int carry = 0;
    for (int base = 0; base < nblocks; base += 64) {
        int raw = (base + lane < nblocks) ? sums[base + lane] : 0;
        int v = raw;
        for (int o = 1; o < 64; o <<= 1) {
            int t = __shfl_up(v, o, 64);
            if (lane >= o) v += t;
        }
        if (base + lane < nblocks) offs[base + lane] = carry + v - raw;
        carry += __shfl(v, 63, 64);
    }
}

// row_ptr[i] = exclusive prefix; cursor[i] = same (fill cursors).
__global__ void scan3_kernel(const int* __restrict__ cnt, const int* __restrict__ incl,
                             const int* __restrict__ offs,
                             int* __restrict__ rp, int* __restrict__ cursor) {
    const int gid = blockIdx.x * 256 + threadIdx.x;
    if (gid < N_NODES) {
        const int ex = incl[gid] - cnt[gid] + offs[gid >> 8];
        rp[gid] = ex;
        cursor[gid] = ex;
    }
    if (gid == 0) rp[N_NODES] = N_EDGES;
}

__global__ void fill_kernel(const int* __restrict__ src, const int* __restrict__ dst,
                            int* __restrict__ cursor, int* __restrict__ col) {
    const int e = blockIdx.x * 256 + threadIdx.x;
    if (e < N_EDGES) {
        const int pos = atomicAdd(&cursor[dst[e]], 1);
        col[pos] = src[e];
    }
}

// ================= GEMM1: h1 = x @ W1  [80000x128 @ 128x64] =================
// 256 thr = 16 rows x 16 col-groups(x4). W1 (32 KB) + padded x-tile (8.4 KB) in LDS.
__global__ void gemm1_kernel(const float* __restrict__ x,
                             const float* __restrict__ W1,
                             float* __restrict__ h1) {
    __shared__ float w[IN_C * HID_C];     // 32 KB
    __shared__ float xt[16 * 132];        // pad 128->132 (bank spread, 16B align)
    const int tid = threadIdx.x;

    const float4* W4 = (const float4*)W1;
    for (int i = tid; i < IN_C * HID_C / 4; i += 256)
        ((float4*)w)[i] = W4[i];

    const int row0 = blockIdx.x * 16;
    const float4* x4 = (const float4*)(x + (size_t)row0 * IN_C);
    for (int i = tid; i < 512; i += 256) {        // 16 rows * 32 float4
        const int r = i >> 5, c = i & 31;
        *(float4*)&xt[r * 132 + c * 4] = x4[i];
    }
    __syncthreads();

    const int rl = tid >> 4;          // 0..15
    const int cg = tid & 15;          // 0..15 -> cols cg*4..cg*4+3
    float4 acc = make_float4(0.f, 0.f, 0.f, 0.f);
#pragma unroll 8
    for (int k = 0; k < IN_C; ++k) {
        const float xv = xt[rl * 132 + k];
        const float4 wv = *(const float4*)&w[k * HID_C + cg * 4];
        acc.x += xv * wv.x; acc.y += xv * wv.y;
        acc.z += xv * wv.z; acc.w += xv * wv.w;
    }
    *(float4*)&h1[(size_t)(row0 + rl) * HID_C + cg * 4] = acc;
}

// ================= SpMM1 gather: agg1[n] = sum h1[col[i]]  (64 ch) =================
// One wave per node; lanes = channels. Edge indices read coalesced then shfl-broadcast.
__global__ void gather64_kernel(const int* __restrict__ rp, const int* __restrict__ col,
                                const float* __restrict__ h1, float* __restrict__ agg1) {
    const int node = blockIdx.x * 4 + (threadIdx.x >> 6);
    const int lane = threadIdx.x & 63;
    if (node >= N_NODES) return;
    const int b = rp[node], e = rp[node + 1];
    float acc = 0.f;
    for (int i = b; i < e; i += 64) {
        int n = e - i; if (n > 64) n = 64;
        const int myIdx = (lane < n) ? col[i + lane] : 0;
        for (int j = 0; j < n; ++j) {
            const int s = __shfl(myIdx, j, 64);
            acc += h1[(size_t)s * HID_C + lane];
        }
    }
    agg1[(size_t)node * HID_C + lane] = acc;
}

// ================= GEMM2: h2 = relu(agg1) @ W2  [80000x64 @ 64x40] =================
// 320 thr = 32 rows x 10 col-groups(x4). relu fused into the LDS staging.
__global__ void gemm2_kernel(const float* __restrict__ agg1,
                             const float* __restrict__ W2,
                             float* __restrict__ h2) {
    __shared__ float w[HID_C * OUT_C];    // 10.24 KB
    __shared__ float xt[32 * 68];         // pad 64->68
    const int tid = threadIdx.x;

    for (int i = tid; i < HID_C * OUT_C / 4; i += 320)
        ((float4*)w)[i] = ((const float4*)W2)[i];

    const int row0 = blockIdx.x * 32;
    const float4* a4 = (const float4*)(agg1 + (size_t)row0 * HID_C);
    for (int i = tid; i < 512; i += 320) {        // 32 rows * 16 float4
        const int r = i >> 4, c = i & 15;
        float4 v = a4[i];
        v.x = v.x > 0.f ? v.x : 0.f; v.y = v.y > 0.f ? v.y : 0.f;
        v.z = v.z > 0.f ? v.z : 0.f; v.w = v.w > 0.f ? v.w : 0.f;
        *(float4*)&xt[r * 68 + c * 4] = v;
    }
    __syncthreads();

    const int rl = tid / 10;          // 0..31
    const int cg = tid - rl * 10;     // 0..9 -> cols cg*4..cg*4+3
    float4 acc = make_float4(0.f, 0.f, 0.f, 0.f);
#pragma unroll 8
    for (int k = 0; k < HID_C; ++k) {
        const float xv = xt[rl * 68 + k];
        const float4 wv = *(const float4*)&w[k * OUT_C + cg * 4];
        acc.x += xv * wv.x; acc.y += xv * wv.y;
        acc.z += xv * wv.z; acc.w += xv * wv.w;
    }
    *(float4*)&h2[(size_t)(row0 + rl) * OUT_C + cg * 4] = acc;
}

// ================= SpMM2 gather: out[n] = sum h2[col[i]]  (40 ch) =================
__global__ void gather40_kernel(const int* __restrict__ rp, const int* __restrict__ col,
                                const float* __restrict__ h2, float* __restrict__ out) {
    const int node = blockIdx.x * 4 + (threadIdx.x >> 6);
    const int lane = threadIdx.x & 63;
    if (node >= N_NODES) return;
    const int b = rp[node], e = rp[node + 1];
    float acc = 0.f;
    for (int i = b; i < e; i += 64) {
        int n = e - i; if (n > 64) n = 64;
        const int myIdx = (lane < n) ? col[i + lane] : 0;
        for (int j = 0; j < n; ++j) {
            const int s = __shfl(myIdx, j, 64);
            if (lane < OUT_C) acc += h2[(size_t)s * OUT_C + lane];
        }
    }
    if (lane < OUT_C) out[(size_t)node * OUT_C + lane] = acc;
}

// ================= log_softmax in-place over rows of 40 =================
__global__ void logsoftmax_kernel(float* __restrict__ io) {
    const int row = blockIdx.x * 4 + (threadIdx.x >> 6);
    const int lane = threadIdx.x & 63;
    if (row >= N_NODES) return;

    float v = (lane < OUT_C) ? io[(size_t)row * OUT_C + lane] : -INFINITY;

    float m = v;
#pragma unroll
    for (int o = 32; o > 0; o >>= 1)
        m = fmaxf(m, __shfl_down(m, o, 64));
    m = __shfl(m, 0, 64);

    float ex = (lane < OUT_C) ? __expf(v - m) : 0.f;
    float s = ex;
#pragma unroll
    for (int o = 32; o > 0; o >>= 1)
        s += __shfl_down(s, o, 64);
    s = __shfl(s, 0, 64);

    const float ls = __logf(s);
    if (lane < OUT_C)
        io[(size_t)row * OUT_C + lane] = v - m - ls;
}

extern "C" void kernel_launch(void* const* d_in, const int* in_sizes, int n_in,
                              void* d_out, int out_size, void* d_ws, size_t ws_size,
                              hipStream_t stream) {
    const float* x  = (const float*)d_in[0];
    const int* eidx = (const int*)d_in[1];
    const float* W1 = (const float*)d_in[2];
    const float* W2 = (const float*)d_in[3];
    float* out = (float*)d_out;

    const int* src = eidx;             // edge_index[0]
    const int* dst = eidx + N_EDGES;   // edge_index[1]

    // Workspace layout (bytes):
    //   h1   [80000*64 f32]  20.48 MB   (reused as h2 after spmm1)
    //   agg1 [80000*64 f32]  20.48 MB
    //   col  [1.28M  i32]     5.12 MB
    //   rp   [80001  i32], cursor/cnt/incl [80000 i32 each], sums/offs [320 i32]
    float* h1   = (float*)d_ws;
    float* agg1 = h1 + (size_t)N_NODES * HID_C;
    int*   col  = (int*)(agg1 + (size_t)N_NODES * HID_C);
    int*   rp     = col + N_EDGES;
    int*   cursor = rp + (N_NODES + 1);
    int*   cnt    = cursor + N_NODES;
    int*   incl   = cnt + N_NODES;
    int*   sums   = incl + N_NODES;
    int*   offs   = sums + 320;
    float* h2 = h1;  // h1 dead after gather64

    const int SCAN_BLOCKS = (N_NODES + 255) / 256;   // 313

    // --- CSR build ---
    hipMemsetAsync(cnt, 0, (size_t)N_NODES * sizeof(int), stream);
    hist_kernel<<<(N_EDGES + 255) / 256, 256, 0, stream>>>(dst, cnt);
    scan1_kernel<<<SCAN_BLOCKS, 256, 0, stream>>>(cnt, incl, sums);
    scan2_kernel<<<1, 64, 0, stream>>>(sums, offs, SCAN_BLOCKS);
    scan3_kernel<<<SCAN_BLOCKS, 256, 0, stream>>>(cnt, incl, offs, rp, cursor);
    fill_kernel<<<(N_EDGES + 255) / 256, 256, 0, stream>>>(src, dst, cursor, col);

    // --- pipeline ---
    gemm1_kernel<<<N_NODES / 16, 256, 0, stream>>>(x, W1, h1);
    gather64_kernel<<<(N_NODES + 3) / 4, 256, 0, stream>>>(rp, col, h1, agg1);
    gemm2_kernel<<<N_NODES / 32, 320, 0, stream>>>(agg1, W2, h2);
    gather40_kernel<<<(N_NODES + 3) / 4, 256, 0, stream>>>(rp, col, h2, out);
    logsoftmax_kernel<<<(N_NODES + 3) / 4, 256, 0, stream>>>(out);
}

// Round 3
// 355.457 us; speedup vs baseline: 2.2524x; 1.2904x over previous
//
#include <hip/hip_runtime.h>
#include <hip/hip_bf16.h>
#include <math.h>

#define N_NODES 80000
#define N_EDGES 1280000
#define IN_C 128
#define HID_C 64
#define OUT_C 40

// Bucketed counting sort params: bucket = dst >> 9 (512 nodes per bucket)
#define KB 157            // ceil(80000 / 512)
#define BK_CAP 10240      // capacity per bucket (mean 8153, sigma ~90 -> safe)
#define EPT 16            // edges per thread in phase A (4096 per WG)

// ================= Phase A: bin edges by dst>>9, grouped writes =================
__global__ void binA_kernel(const int* __restrict__ src, const int* __restrict__ dst,
                            int* __restrict__ bcnt, int* __restrict__ gbuf) {
    __shared__ int lcnt[KB];
    __shared__ int lexcl[KB];
    __shared__ int lbase[KB];
    __shared__ int lcur[KB];
    __shared__ int stage[256 * EPT];   // packed words grouped by bucket
    __shared__ int gaddr[256 * EPT];   // matching global addresses
    const int tid = threadIdx.x;

    for (int i = tid; i < KB; i += 256) lcnt[i] = 0;
    __syncthreads();

    const int e0 = blockIdx.x * 256 * EPT;
    int my_s[EPT], my_b[EPT], my_dl[EPT];
#pragma unroll
    for (int j = 0; j < EPT; ++j) {
        const int e = e0 + j * 256 + tid;          // coalesced
        if (e < N_EDGES) {
            const int d = dst[e];
            my_s[j] = src[e];
            my_b[j] = d >> 9;
            my_dl[j] = d & 511;
            atomicAdd(&lcnt[my_b[j]], 1);
        } else my_b[j] = -1;
    }
    __syncthreads();

    // inclusive scan of lcnt over KB (Hillis-Steele, tid<KB active)
    if (tid < KB) lexcl[tid] = lcnt[tid];
    __syncthreads();
    for (int o = 1; o < KB; o <<= 1) {
        int t = (tid < KB && tid >= o) ? lexcl[tid - o] : 0;
        __syncthreads();
        if (tid < KB) lexcl[tid] += t;
        __syncthreads();
    }
    const int total = lexcl[KB - 1];
    // make exclusive, reserve global space, init cursors
    if (tid < KB) {
        lexcl[tid] -= lcnt[tid];
        lbase[tid] = (lcnt[tid] > 0) ? atomicAdd(&bcnt[tid], lcnt[tid]) : 0;
        lcur[tid] = 0;
    }
    __syncthreads();

    // rank-scatter into LDS (grouped by bucket) + record global addresses
#pragma unroll
    for (int j = 0; j < EPT; ++j) {
        if (my_b[j] >= 0) {
            const int b = my_b[j];
            const int r = atomicAdd(&lcur[b], 1);
            const int li = lexcl[b] + r;
            stage[li] = (my_s[j] << 9) | my_dl[j];
            int gp = lbase[b] + r;
            if (gp >= BK_CAP) gp = BK_CAP - 1;     // statistically never
            gaddr[li] = b * BK_CAP + gp;
        }
    }
    __syncthreads();

    // grouped write-out: consecutive lanes -> consecutive addrs within segments
    for (int i = tid; i < total; i += 256)
        gbuf[gaddr[i]] = stage[i];
}

// ================= bucket base: exclusive scan of 157 counts (1 wave) =================
__global__ void bucket_scan_kernel(const int* __restrict__ cnt, int* __restrict__ base) {
    const int lane = threadIdx.x;
    int carry = 0;
    for (int b0 = 0; b0 < KB; b0 += 64) {
        int raw = (b0 + lane < KB) ? min(cnt[b0 + lane], BK_CAP) : 0;
        int v = raw;
        for (int o = 1; o < 64; o <<= 1) {
            int t = __shfl_up(v, o, 64);
            if (lane >= o) v += t;
        }
        if (b0 + lane < KB) base[b0 + lane] = carry + v - raw;
        carry += __shfl(v, 63, 64);
    }
}

// ================= Phase B: per-bucket -> rp + col (coalesced) =================
__global__ void binB_kernel(const int* __restrict__ bcnt, const int* __restrict__ bbase,
                            const int* __restrict__ gbuf,
                            int* __restrict__ rp, int* __restrict__ col) {
    __shared__ int hist[512];
    __shared__ int excl[512];
    __shared__ int cur[512];
    __shared__ int ps[256];
    __shared__ int outb[BK_CAP];       // 40 KB
    const int b = blockIdx.x;
    const int tid = threadIdx.x;
    const int n = min(bcnt[b], BK_CAP);
    const int cbase = bbase[b];
    const int* __restrict__ my = gbuf + (size_t)b * BK_CAP;

    for (int i = tid; i < 512; i += 256) hist[i] = 0;
    __syncthreads();
    for (int i = tid; i < n; i += 256)
        atomicAdd(&hist[my[i] & 511], 1);
    __syncthreads();

    // exclusive scan of 512 via pair-sums + 256-scan
    const int h0 = hist[2 * tid], h1 = hist[2 * tid + 1];
    const int p = h0 + h1;
    ps[tid] = p;
    __syncthreads();
    for (int o = 1; o < 256; o <<= 1) {
        int t = (tid >= o) ? ps[tid - o] : 0;
        __syncthreads();
        ps[tid] += t;
        __syncthreads();
    }
    const int pb = ps[tid] - p;
    excl[2 * tid] = pb;
    excl[2 * tid + 1] = pb + h0;
    cur[2 * tid] = pb;
    cur[2 * tid + 1] = pb + h0;
    __syncthreads();

    // write rp (node <= N_NODES guard also emits rp[N_NODES] = N_EDGES)
    for (int i = tid; i < 512; i += 256) {
        const int node = b * 512 + i;
        if (node <= N_NODES) rp[node] = cbase + excl[i];
    }

    // rank-scatter src into LDS by node, then coalesced write to col
    for (int i = tid; i < n; i += 256) {
        const int pk = my[i];
        const int pos = atomicAdd(&cur[pk & 511], 1);
        outb[pos] = pk >> 9;
    }
    __syncthreads();
    for (int i = tid; i < n; i += 256)
        col[cbase + i] = outb[i];
}

// ================= GEMM1: h1 = x @ W1  [80000x128 @ 128x64] =================
__global__ void gemm1_kernel(const float* __restrict__ x,
                             const float* __restrict__ W1,
                             float* __restrict__ h1) {
    __shared__ float w[IN_C * HID_C];     // 32 KB
    __shared__ float xt[16 * 132];        // pad 128->132
    const int tid = threadIdx.x;

    const float4* W4 = (const float4*)W1;
    for (int i = tid; i < IN_C * HID_C / 4; i += 256)
        ((float4*)w)[i] = W4[i];

    const int row0 = blockIdx.x * 16;
    const float4* x4 = (const float4*)(x + (size_t)row0 * IN_C);
    for (int i = tid; i < 512; i += 256) {
        const int r = i >> 5, c = i & 31;
        *(float4*)&xt[r * 132 + c * 4] = x4[i];
    }
    __syncthreads();

    const int rl = tid >> 4;
    const int cg = tid & 15;
    float4 acc = make_float4(0.f, 0.f, 0.f, 0.f);
#pragma unroll 8
    for (int k = 0; k < IN_C; ++k) {
        const float xv = xt[rl * 132 + k];
        const float4 wv = *(const float4*)&w[k * HID_C + cg * 4];
        acc.x += xv * wv.x; acc.y += xv * wv.y;
        acc.z += xv * wv.z; acc.w += xv * wv.w;
    }
    *(float4*)&h1[(size_t)(row0 + rl) * HID_C + cg * 4] = acc;
}

// ================= SpMM1 gather: agg1[n] = sum h1[col[i]]  (64 ch) =================
__global__ void gather64_kernel(const int* __restrict__ rp, const int* __restrict__ col,
                                const float* __restrict__ h1, float* __restrict__ agg1) {
    const int node = blockIdx.x * 4 + (threadIdx.x >> 6);
    const int lane = threadIdx.x & 63;
    if (node >= N_NODES) return;
    const int b = rp[node], e = rp[node + 1];
    float acc = 0.f;
    for (int i = b; i < e; i += 64) {
        int n = e - i; if (n > 64) n = 64;
        const int myIdx = (lane < n) ? col[i + lane] : 0;
        for (int j = 0; j < n; ++j) {
            const int s = __shfl(myIdx, j, 64);
            acc += h1[(size_t)s * HID_C + lane];
        }
    }
    agg1[(size_t)node * HID_C + lane] = acc;
}

// ================= GEMM2: h2 = relu(agg1) @ W2  [80000x64 @ 64x40] =================
__global__ void gemm2_kernel(const float* __restrict__ agg1,
                             const float* __restrict__ W2,
                             float* __restrict__ h2) {
    __shared__ float w[HID_C * OUT_C];
    __shared__ float xt[32 * 68];
    const int tid = threadIdx.x;

    for (int i = tid; i < HID_C * OUT_C / 4; i += 320)
        ((float4*)w)[i] = ((const float4*)W2)[i];

    const int row0 = blockIdx.x * 32;
    const float4* a4 = (const float4*)(agg1 + (size_t)row0 * HID_C);
    for (int i = tid; i < 512; i += 320) {
        const int r = i >> 4, c = i & 15;
        float4 v = a4[i];
        v.x = v.x > 0.f ? v.x : 0.f; v.y = v.y > 0.f ? v.y : 0.f;
        v.z = v.z > 0.f ? v.z : 0.f; v.w = v.w > 0.f ? v.w : 0.f;
        *(float4*)&xt[r * 68 + c * 4] = v;
    }
    __syncthreads();

    const int rl = tid / 10;
    const int cg = tid - rl * 10;
    float4 acc = make_float4(0.f, 0.f, 0.f, 0.f);
#pragma unroll 8
    for (int k = 0; k < HID_C; ++k) {
        const float xv = xt[rl * 68 + k];
        const float4 wv = *(const float4*)&w[k * OUT_C + cg * 4];
        acc.x += xv * wv.x; acc.y += xv * wv.y;
        acc.z += xv * wv.z; acc.w += xv * wv.w;
    }
    *(float4*)&h2[(size_t)(row0 + rl) * OUT_C + cg * 4] = acc;
}

// ================= SpMM2 gather: out[n] = sum h2[col[i]]  (40 ch) =================
__global__ void gather40_kernel(const int* __restrict__ rp, const int* __restrict__ col,
                                const float* __restrict__ h2, float* __restrict__ out) {
    const int node = blockIdx.x * 4 + (threadIdx.x >> 6);
    const int lane = threadIdx.x & 63;
    if (node >= N_NODES) return;
    const int b = rp[node], e = rp[node + 1];
    float acc = 0.f;
    for (int i = b; i < e; i += 64) {
        int n = e - i; if (n > 64) n = 64;
        const int myIdx = (lane < n) ? col[i + lane] : 0;
        for (int j = 0; j < n; ++j) {
            const int s = __shfl(myIdx, j, 64);
            if (lane < OUT_C) acc += h2[(size_t)s * OUT_C + lane];
        }
    }
    if (lane < OUT_C) out[(size_t)node * OUT_C + lane] = acc;
}

// ================= log_softmax in-place over rows of 40 =================
__global__ void logsoftmax_kernel(float* __restrict__ io) {
    const int row = blockIdx.x * 4 + (threadIdx.x >> 6);
    const int lane = threadIdx.x & 63;
    if (row >= N_NODES) return;

    float v = (lane < OUT_C) ? io[(size_t)row * OUT_C + lane] : -INFINITY;

    float m = v;
#pragma unroll
    for (int o = 32; o > 0; o >>= 1)
        m = fmaxf(m, __shfl_down(m, o, 64));
    m = __shfl(m, 0, 64);

    float ex = (lane < OUT_C) ? __expf(v - m) : 0.f;
    float s = ex;
#pragma unroll
    for (int o = 32; o > 0; o >>= 1)
        s += __shfl_down(s, o, 64);
    s = __shfl(s, 0, 64);

    const float ls = __logf(s);
    if (lane < OUT_C)
        io[(size_t)row * OUT_C + lane] = v - m - ls;
}

extern "C" void kernel_launch(void* const* d_in, const int* in_sizes, int n_in,
                              void* d_out, int out_size, void* d_ws, size_t ws_size,
                              hipStream_t stream) {
    const float* x  = (const float*)d_in[0];
    const int* eidx = (const int*)d_in[1];
    const float* W1 = (const float*)d_in[2];
    const float* W2 = (const float*)d_in[3];
    float* out = (float*)d_out;

    const int* src = eidx;             // edge_index[0]
    const int* dst = eidx + N_EDGES;   // edge_index[1]

    // Workspace layout:
    //   h1   [80000*64 f32]  20.48 MB  (reused as h2)
    //   agg1 [80000*64 f32]  20.48 MB  (gbuf [157*10240 i32] = 6.43 MB overlays;
    //                                   gbuf dead before gather64 writes agg1)
    //   col  [1.28M i32], rp [80001], bcnt [157], bbase [157]
    float* h1   = (float*)d_ws;
    float* agg1 = h1 + (size_t)N_NODES * HID_C;
    int*   gbuf = (int*)agg1;
    int*   col  = (int*)(agg1 + (size_t)N_NODES * HID_C);
    int*   rp    = col + N_EDGES;
    int*   bcnt  = rp + (N_NODES + 1);
    int*   bbase = bcnt + KB;
    float* h2 = h1;

    // --- CSR build via binned counting sort ---
    hipMemsetAsync(bcnt, 0, KB * sizeof(int), stream);
    binA_kernel<<<(N_EDGES + 256 * EPT - 1) / (256 * EPT), 256, 0, stream>>>(src, dst, bcnt, gbuf);
    bucket_scan_kernel<<<1, 64, 0, stream>>>(bcnt, bbase);
    binB_kernel<<<KB, 256, 0, stream>>>(bcnt, bbase, gbuf, rp, col);

    // --- pipeline ---
    gemm1_kernel<<<N_NODES / 16, 256, 0, stream>>>(x, W1, h1);
    gather64_kernel<<<(N_NODES + 3) / 4, 256, 0, stream>>>(rp, col, h1, agg1);
    gemm2_kernel<<<N_NODES / 32, 320, 0, stream>>>(agg1, W2, h2);
    gather40_kernel<<<(N_NODES + 3) / 4, 256, 0, stream>>>(rp, col, h2, out);
    logsoftmax_kernel<<<(N_NODES + 3) / 4, 256, 0, stream>>>(out);
}

// Round 4
// 266.450 us; speedup vs baseline: 3.0049x; 1.3340x over previous
//
#include <hip/hip_runtime.h>
#include <hip/hip_bf16.h>
#include <math.h>

#define N_NODES 80000
#define N_EDGES 1280000
#define IN_C 128
#define HID_C 64
#define OUT_C 40

// Bucketed counting sort params: bucket = dst >> 9 (512 nodes per bucket)
#define KB 157            // ceil(80000 / 512)
#define BK_CAP 10240      // capacity per bucket (mean 8153 -> safe)
#define EPT 16            // edges per thread in phase A (4096 per WG)

// ================= Phase A: bin edges by dst>>9, grouped writes =================
__global__ void binA_kernel(const int* __restrict__ src, const int* __restrict__ dst,
                            int* __restrict__ bcnt, int* __restrict__ gbuf) {
    __shared__ int lcnt[KB];
    __shared__ int lexcl[KB];
    __shared__ int lbase[KB];
    __shared__ int lcur[KB];
    __shared__ int stage[256 * EPT];
    __shared__ int gaddr[256 * EPT];
    const int tid = threadIdx.x;

    for (int i = tid; i < KB; i += 256) lcnt[i] = 0;
    __syncthreads();

    const int e0 = blockIdx.x * 256 * EPT;
    int my_s[EPT], my_b[EPT], my_dl[EPT];
#pragma unroll
    for (int j = 0; j < EPT; ++j) {
        const int e = e0 + j * 256 + tid;
        if (e < N_EDGES) {
            const int d = dst[e];
            my_s[j] = src[e];
            my_b[j] = d >> 9;
            my_dl[j] = d & 511;
            atomicAdd(&lcnt[my_b[j]], 1);
        } else my_b[j] = -1;
    }
    __syncthreads();

    if (tid < KB) lexcl[tid] = lcnt[tid];
    __syncthreads();
    for (int o = 1; o < KB; o <<= 1) {
        int t = (tid < KB && tid >= o) ? lexcl[tid - o] : 0;
        __syncthreads();
        if (tid < KB) lexcl[tid] += t;
        __syncthreads();
    }
    const int total = lexcl[KB - 1];
    if (tid < KB) {
        lexcl[tid] -= lcnt[tid];
        lbase[tid] = (lcnt[tid] > 0) ? atomicAdd(&bcnt[tid], lcnt[tid]) : 0;
        lcur[tid] = 0;
    }
    __syncthreads();

#pragma unroll
    for (int j = 0; j < EPT; ++j) {
        if (my_b[j] >= 0) {
            const int b = my_b[j];
            const int r = atomicAdd(&lcur[b], 1);
            const int li = lexcl[b] + r;
            stage[li] = (my_s[j] << 9) | my_dl[j];
            int gp = lbase[b] + r;
            if (gp >= BK_CAP) gp = BK_CAP - 1;
            gaddr[li] = b * BK_CAP + gp;
        }
    }
    __syncthreads();

    for (int i = tid; i < total; i += 256)
        gbuf[gaddr[i]] = stage[i];
}

// ================= bucket base: exclusive scan of 157 counts =================
__global__ void bucket_scan_kernel(const int* __restrict__ cnt, int* __restrict__ base) {
    const int lane = threadIdx.x;
    int carry = 0;
    for (int b0 = 0; b0 < KB; b0 += 64) {
        int raw = (b0 + lane < KB) ? min(cnt[b0 + lane], BK_CAP) : 0;
        int v = raw;
        for (int o = 1; o < 64; o <<= 1) {
            int t = __shfl_up(v, o, 64);
            if (lane >= o) v += t;
        }
        if (b0 + lane < KB) base[b0 + lane] = carry + v - raw;
        carry += __shfl(v, 63, 64);
    }
}

// ================= Phase B: per-bucket -> rp + col (coalesced) =================
__global__ void binB_kernel(const int* __restrict__ bcnt, const int* __restrict__ bbase,
                            const int* __restrict__ gbuf,
                            int* __restrict__ rp, int* __restrict__ col) {
    __shared__ int hist[512];
    __shared__ int excl[512];
    __shared__ int cur[512];
    __shared__ int ps[256];
    __shared__ int outb[BK_CAP];
    const int b = blockIdx.x;
    const int tid = threadIdx.x;
    const int n = min(bcnt[b], BK_CAP);
    const int cbase = bbase[b];
    const int* __restrict__ my = gbuf + (size_t)b * BK_CAP;

    for (int i = tid; i < 512; i += 256) hist[i] = 0;
    __syncthreads();
    for (int i = tid; i < n; i += 256)
        atomicAdd(&hist[my[i] & 511], 1);
    __syncthreads();

    const int h0 = hist[2 * tid], h1 = hist[2 * tid + 1];
    const int p = h0 + h1;
    ps[tid] = p;
    __syncthreads();
    for (int o = 1; o < 256; o <<= 1) {
        int t = (tid >= o) ? ps[tid - o] : 0;
        __syncthreads();
        ps[tid] += t;
        __syncthreads();
    }
    const int pb = ps[tid] - p;
    excl[2 * tid] = pb;
    excl[2 * tid + 1] = pb + h0;
    cur[2 * tid] = pb;
    cur[2 * tid + 1] = pb + h0;
    __syncthreads();

    for (int i = tid; i < 512; i += 256) {
        const int node = b * 512 + i;
        if (node <= N_NODES) rp[node] = cbase + excl[i];
    }

    for (int i = tid; i < n; i += 256) {
        const int pk = my[i];
        const int pos = atomicAdd(&cur[pk & 511], 1);
        outb[pos] = pk >> 9;
    }
    __syncthreads();
    for (int i = tid; i < n; i += 256)
        col[cbase + i] = outb[i];
}

// ================= GEMM1: h1 = x @ W1  [80000x128 @ 128x64] =================
// 64x64 tile, 256 thr, 4x4 outputs/thread, k-unrolled by 4. LDS reads are
// 16-lane broadcasts (conflict-free); 8 b128 reads feed 64 FMA insts per k4.
__global__ __launch_bounds__(256) void gemm1_kernel(const float* __restrict__ x,
                                                    const float* __restrict__ W1,
                                                    float* __restrict__ h1) {
    __shared__ float w[IN_C * HID_C];     // 32 KB
    __shared__ float xt[64 * 132];        // 33.8 KB (pad 128->132)
    const int tid = threadIdx.x;

    for (int i = tid; i < IN_C * HID_C / 4; i += 256)
        ((float4*)w)[i] = ((const float4*)W1)[i];

    const int row0 = blockIdx.x * 64;
    const float4* x4 = (const float4*)(x + (size_t)row0 * IN_C);
    for (int i = tid; i < 2048; i += 256) {       // 64 rows * 32 float4
        const int r = i >> 5, c = i & 31;
        *(float4*)&xt[r * 132 + c * 4] = x4[i];
    }
    __syncthreads();

    const int rg = tid >> 4;          // rows rg*4..+3
    const int cgi = tid & 15;         // cols cgi*4..+3
    float4 acc[4];
#pragma unroll
    for (int q = 0; q < 4; ++q) acc[q] = make_float4(0.f, 0.f, 0.f, 0.f);

    for (int k = 0; k < IN_C; k += 4) {
        float4 xv[4], wv[4];
#pragma unroll
        for (int q = 0; q < 4; ++q)
            xv[q] = *(const float4*)&xt[(rg * 4 + q) * 132 + k];
#pragma unroll
        for (int kk = 0; kk < 4; ++kk)
            wv[kk] = *(const float4*)&w[(k + kk) * HID_C + cgi * 4];
#pragma unroll
        for (int q = 0; q < 4; ++q) {
            acc[q].x += xv[q].x * wv[0].x + xv[q].y * wv[1].x + xv[q].z * wv[2].x + xv[q].w * wv[3].x;
            acc[q].y += xv[q].x * wv[0].y + xv[q].y * wv[1].y + xv[q].z * wv[2].y + xv[q].w * wv[3].y;
            acc[q].z += xv[q].x * wv[0].z + xv[q].y * wv[1].z + xv[q].z * wv[2].z + xv[q].w * wv[3].z;
            acc[q].w += xv[q].x * wv[0].w + xv[q].y * wv[1].w + xv[q].z * wv[2].w + xv[q].w * wv[3].w;
        }
    }
#pragma unroll
    for (int q = 0; q < 4; ++q)
        *(float4*)&h1[(size_t)(row0 + rg * 4 + q) * HID_C + cgi * 4] = acc[q];
}

// ================= SpMM1 gather v2: 4 edges/wave via float4 groups =================
__global__ void gather64_kernel(const int* __restrict__ rp, const int* __restrict__ col,
                                const float* __restrict__ h1, float* __restrict__ agg1) {
    const int node = blockIdx.x * 4 + (threadIdx.x >> 6);
    const int lane = threadIdx.x & 63;
    const int grp = lane >> 4;        // which edge in the 4-batch
    const int cg  = lane & 15;        // channel group (float4)
    if (node >= N_NODES) return;
    const int b = rp[node], e = rp[node + 1];
    float4 acc = make_float4(0.f, 0.f, 0.f, 0.f);
    for (int i = b; i < e; i += 64) {
        const int n = min(64, e - i);
        const int myIdx = (lane < n) ? col[i + lane] : 0;
        const int steps = (n + 3) >> 2;
        for (int j = 0; j < steps; ++j) {
            const int ei = (j << 2) + grp;
            const int s = __shfl(myIdx, ei, 64);
            if (ei < n) {
                const float4 v = *(const float4*)&h1[(size_t)s * HID_C + (cg << 2)];
                acc.x += v.x; acc.y += v.y; acc.z += v.z; acc.w += v.w;
            }
        }
    }
    acc.x += __shfl_down(acc.x, 32, 64); acc.y += __shfl_down(acc.y, 32, 64);
    acc.z += __shfl_down(acc.z, 32, 64); acc.w += __shfl_down(acc.w, 32, 64);
    acc.x += __shfl_down(acc.x, 16, 64); acc.y += __shfl_down(acc.y, 16, 64);
    acc.z += __shfl_down(acc.z, 16, 64); acc.w += __shfl_down(acc.w, 16, 64);
    if (grp == 0)
        *(float4*)&agg1[(size_t)node * HID_C + (cg << 2)] = acc;
}

// ================= GEMM2: h2 = relu(agg1) @ W2  [80000x64 @ 64x40] =================
// 128x40 tile, 320 thr, 4x4 outputs/thread, k-unrolled by 4.
__global__ __launch_bounds__(320) void gemm2_kernel(const float* __restrict__ agg1,
                                                    const float* __restrict__ W2,
                                                    float* __restrict__ h2) {
    __shared__ float w[HID_C * OUT_C];    // 10.24 KB
    __shared__ float xt[128 * 68];        // 34.8 KB (pad 64->68)
    const int tid = threadIdx.x;

    for (int i = tid; i < HID_C * OUT_C / 4; i += 320)
        ((float4*)w)[i] = ((const float4*)W2)[i];

    const int row0 = blockIdx.x * 128;
    const float4* a4 = (const float4*)(agg1 + (size_t)row0 * HID_C);
    for (int i = tid; i < 2048; i += 320) {       // 128 rows * 16 float4
        const int r = i >> 4, c = i & 15;
        float4 v = a4[i];
        v.x = v.x > 0.f ? v.x : 0.f; v.y = v.y > 0.f ? v.y : 0.f;
        v.z = v.z > 0.f ? v.z : 0.f; v.w = v.w > 0.f ? v.w : 0.f;
        *(float4*)&xt[r * 68 + c * 4] = v;
    }
    __syncthreads();

    const int rg = tid / 10;          // 0..31 -> rows rg*4..+3
    const int cgi = tid - rg * 10;    // 0..9  -> cols cgi*4..+3
    float4 acc[4];
#pragma unroll
    for (int q = 0; q < 4; ++q) acc[q] = make_float4(0.f, 0.f, 0.f, 0.f);

    for (int k = 0; k < HID_C; k += 4) {
        float4 xv[4], wv[4];
#pragma unroll
        for (int q = 0; q < 4; ++q)
            xv[q] = *(const float4*)&xt[(rg * 4 + q) * 68 + k];
#pragma unroll
        for (int kk = 0; kk < 4; ++kk)
            wv[kk] = *(const float4*)&w[(k + kk) * OUT_C + cgi * 4];
#pragma unroll
        for (int q = 0; q < 4; ++q) {
            acc[q].x += xv[q].x * wv[0].x + xv[q].y * wv[1].x + xv[q].z * wv[2].x + xv[q].w * wv[3].x;
            acc[q].y += xv[q].x * wv[0].y + xv[q].y * wv[1].y + xv[q].z * wv[2].y + xv[q].w * wv[3].y;
            acc[q].z += xv[q].x * wv[0].z + xv[q].y * wv[1].z + xv[q].z * wv[2].z + xv[q].w * wv[3].z;
            acc[q].w += xv[q].x * wv[0].w + xv[q].y * wv[1].w + xv[q].z * wv[2].w + xv[q].w * wv[3].w;
        }
    }
#pragma unroll
    for (int q = 0; q < 4; ++q)
        *(float4*)&h2[(size_t)(row0 + rg * 4 + q) * OUT_C + cgi * 4] = acc[q];
}

// ================= SpMM2 gather + log_softmax fused =================
__global__ void gather40_ls_kernel(const int* __restrict__ rp, const int* __restrict__ col,
                                   const float* __restrict__ h2, float* __restrict__ out) {
    const int node = blockIdx.x * 4 + (threadIdx.x >> 6);
    const int lane = threadIdx.x & 63;
    const int grp = lane >> 4;
    const int cg  = lane & 15;
    if (node >= N_NODES) return;
    const int b = rp[node], e = rp[node + 1];
    float4 acc = make_float4(0.f, 0.f, 0.f, 0.f);
    const bool act = (cg < 10);
    for (int i = b; i < e; i += 64) {
        const int n = min(64, e - i);
        const int myIdx = (lane < n) ? col[i + lane] : 0;
        const int steps = (n + 3) >> 2;
        for (int j = 0; j < steps; ++j) {
            const int ei = (j << 2) + grp;
            const int s = __shfl(myIdx, ei, 64);
            if (ei < n && act) {
                const float4 v = *(const float4*)&h2[(size_t)s * OUT_C + (cg << 2)];
                acc.x += v.x; acc.y += v.y; acc.z += v.z; acc.w += v.w;
            }
        }
    }
    acc.x += __shfl_down(acc.x, 32, 64); acc.y += __shfl_down(acc.y, 32, 64);
    acc.z += __shfl_down(acc.z, 32, 64); acc.w += __shfl_down(acc.w, 32, 64);
    acc.x += __shfl_down(acc.x, 16, 64); acc.y += __shfl_down(acc.y, 16, 64);
    acc.z += __shfl_down(acc.z, 16, 64); acc.w += __shfl_down(acc.w, 16, 64);

    const bool own = (grp == 0) && act;   // lanes 0..9 hold the 40 outputs
    float vmax = own ? fmaxf(fmaxf(acc.x, acc.y), fmaxf(acc.z, acc.w)) : -INFINITY;
#pragma unroll
    for (int o = 32; o > 0; o >>= 1)
        vmax = fmaxf(vmax, __shfl_xor(vmax, o, 64));
    float s = own ? (__expf(acc.x - vmax) + __expf(acc.y - vmax) +
                     __expf(acc.z - vmax) + __expf(acc.w - vmax)) : 0.f;
#pragma unroll
    for (int o = 32; o > 0; o >>= 1)
        s += __shfl_xor(s, o, 64);
    const float ls = __logf(s) + vmax;
    if (own) {
        float4 o4 = make_float4(acc.x - ls, acc.y - ls, acc.z - ls, acc.w - ls);
        *(float4*)&out[(size_t)node * OUT_C + (cg << 2)] = o4;
    }
}

extern "C" void kernel_launch(void* const* d_in, const int* in_sizes, int n_in,
                              void* d_out, int out_size, void* d_ws, size_t ws_size,
                              hipStream_t stream) {
    const float* x  = (const float*)d_in[0];
    const int* eidx = (const int*)d_in[1];
    const float* W1 = (const float*)d_in[2];
    const float* W2 = (const float*)d_in[3];
    float* out = (float*)d_out;

    const int* src = eidx;             // edge_index[0]
    const int* dst = eidx + N_EDGES;   // edge_index[1]

    // Workspace layout:
    //   h1   [80000*64 f32]  20.48 MB  (reused as h2)
    //   agg1 [80000*64 f32]  20.48 MB  (gbuf overlays; dead before gather64)
    //   col  [1.28M i32], rp [80001], bcnt [157], bbase [157]
    float* h1   = (float*)d_ws;
    float* agg1 = h1 + (size_t)N_NODES * HID_C;
    int*   gbuf = (int*)agg1;
    int*   col  = (int*)(agg1 + (size_t)N_NODES * HID_C);
    int*   rp    = col + N_EDGES;
    int*   bcnt  = rp + (N_NODES + 1);
    int*   bbase = bcnt + KB;
    float* h2 = h1;

    // --- CSR build via binned counting sort ---
    hipMemsetAsync(bcnt, 0, KB * sizeof(int), stream);
    binA_kernel<<<(N_EDGES + 256 * EPT - 1) / (256 * EPT), 256, 0, stream>>>(src, dst, bcnt, gbuf);
    bucket_scan_kernel<<<1, 64, 0, stream>>>(bcnt, bbase);
    binB_kernel<<<KB, 256, 0, stream>>>(bcnt, bbase, gbuf, rp, col);

    // --- pipeline ---
    gemm1_kernel<<<N_NODES / 64, 256, 0, stream>>>(x, W1, h1);
    gather64_kernel<<<(N_NODES + 3) / 4, 256, 0, stream>>>(rp, col, h1, agg1);
    gemm2_kernel<<<N_NODES / 128, 320, 0, stream>>>(agg1, W2, h2);
    gather40_ls_kernel<<<(N_NODES + 3) / 4, 256, 0, stream>>>(rp, col, h2, out);
}

// Round 5
// 242.453 us; speedup vs baseline: 3.3023x; 1.0990x over previous
//
#include <hip/hip_runtime.h>
#include <hip/hip_bf16.h>
#include <math.h>

#define N_NODES 80000
#define N_EDGES 1280000
#define IN_C 128
#define HID_C 64
#define OUT_C 40

// Bucketed counting sort params: bucket = dst >> 9 (512 nodes per bucket)
#define KB 157            // ceil(80000 / 512)
#define BK_CAP 10240      // capacity per bucket (mean 8153 -> safe)
#define EPT 16            // edges per thread in phase A (4096 per WG)

// ---- bf16 helpers (storage bf16, math fp32) ----
__device__ __forceinline__ float bf_lo(unsigned u) {
    union { unsigned i; float f; } c; c.i = u << 16; return c.f;
}
__device__ __forceinline__ float bf_hi(unsigned u) {
    union { unsigned i; float f; } c; c.i = u & 0xffff0000u; return c.f;
}
__device__ __forceinline__ unsigned pack_bf2(float a, float b) {  // RTNE
    union { float f; unsigned i; } ca, cb; ca.f = a; cb.f = b;
    unsigned ra = (ca.i + 0x7fffu + ((ca.i >> 16) & 1u)) >> 16;
    unsigned rb = (cb.i + 0x7fffu + ((cb.i >> 16) & 1u)) >> 16;
    return ra | (rb << 16);
}

// ================= Phase A: bin edges by dst>>9, grouped writes =================
__global__ void binA_kernel(const int* __restrict__ src, const int* __restrict__ dst,
                            int* __restrict__ bcnt, int* __restrict__ gbuf) {
    __shared__ int lcnt[KB];
    __shared__ int lexcl[KB];
    __shared__ int lbase[KB];
    __shared__ int lcur[KB];
    __shared__ int stage[256 * EPT];
    __shared__ int gaddr[256 * EPT];
    const int tid = threadIdx.x;

    for (int i = tid; i < KB; i += 256) lcnt[i] = 0;
    __syncthreads();

    const int e0 = blockIdx.x * 256 * EPT;
    int my_s[EPT], my_b[EPT], my_dl[EPT];
#pragma unroll
    for (int j = 0; j < EPT; ++j) {
        const int e = e0 + j * 256 + tid;
        if (e < N_EDGES) {
            const int d = dst[e];
            my_s[j] = src[e];
            my_b[j] = d >> 9;
            my_dl[j] = d & 511;
            atomicAdd(&lcnt[my_b[j]], 1);
        } else my_b[j] = -1;
    }
    __syncthreads();

    if (tid < KB) lexcl[tid] = lcnt[tid];
    __syncthreads();
    for (int o = 1; o < KB; o <<= 1) {
        int t = (tid < KB && tid >= o) ? lexcl[tid - o] : 0;
        __syncthreads();
        if (tid < KB) lexcl[tid] += t;
        __syncthreads();
    }
    const int total = lexcl[KB - 1];
    if (tid < KB) {
        lexcl[tid] -= lcnt[tid];
        lbase[tid] = (lcnt[tid] > 0) ? atomicAdd(&bcnt[tid], lcnt[tid]) : 0;
        lcur[tid] = 0;
    }
    __syncthreads();

#pragma unroll
    for (int j = 0; j < EPT; ++j) {
        if (my_b[j] >= 0) {
            const int b = my_b[j];
            const int r = atomicAdd(&lcur[b], 1);
            const int li = lexcl[b] + r;
            stage[li] = (my_s[j] << 9) | my_dl[j];
            int gp = lbase[b] + r;
            if (gp >= BK_CAP) gp = BK_CAP - 1;
            gaddr[li] = b * BK_CAP + gp;
        }
    }
    __syncthreads();

    for (int i = tid; i < total; i += 256)
        gbuf[gaddr[i]] = stage[i];
}

// ================= bucket base: exclusive scan of 157 counts =================
__global__ void bucket_scan_kernel(const int* __restrict__ cnt, int* __restrict__ base) {
    const int lane = threadIdx.x;
    int carry = 0;
    for (int b0 = 0; b0 < KB; b0 += 64) {
        int raw = (b0 + lane < KB) ? min(cnt[b0 + lane], BK_CAP) : 0;
        int v = raw;
        for (int o = 1; o < 64; o <<= 1) {
            int t = __shfl_up(v, o, 64);
            if (lane >= o) v += t;
        }
        if (b0 + lane < KB) base[b0 + lane] = carry + v - raw;
        carry += __shfl(v, 63, 64);
    }
}

// ================= Phase B: per-bucket -> rp + col (coalesced) =================
__global__ void binB_kernel(const int* __restrict__ bcnt, const int* __restrict__ bbase,
                            const int* __restrict__ gbuf,
                            int* __restrict__ rp, int* __restrict__ col) {
    __shared__ int hist[512];
    __shared__ int excl[512];
    __shared__ int cur[512];
    __shared__ int ps[256];
    __shared__ int outb[BK_CAP];
    const int b = blockIdx.x;
    const int tid = threadIdx.x;
    const int n = min(bcnt[b], BK_CAP);
    const int cbase = bbase[b];
    const int* __restrict__ my = gbuf + (size_t)b * BK_CAP;

    for (int i = tid; i < 512; i += 256) hist[i] = 0;
    __syncthreads();
    for (int i = tid; i < n; i += 256)
        atomicAdd(&hist[my[i] & 511], 1);
    __syncthreads();

    const int h0 = hist[2 * tid], h1 = hist[2 * tid + 1];
    const int p = h0 + h1;
    ps[tid] = p;
    __syncthreads();
    for (int o = 1; o < 256; o <<= 1) {
        int t = (tid >= o) ? ps[tid - o] : 0;
        __syncthreads();
        ps[tid] += t;
        __syncthreads();
    }
    const int pb = ps[tid] - p;
    excl[2 * tid] = pb;
    excl[2 * tid + 1] = pb + h0;
    cur[2 * tid] = pb;
    cur[2 * tid + 1] = pb + h0;
    __syncthreads();

    for (int i = tid; i < 512; i += 256) {
        const int node = b * 512 + i;
        if (node <= N_NODES) rp[node] = cbase + excl[i];
    }

    for (int i = tid; i < n; i += 256) {
        const int pk = my[i];
        const int pos = atomicAdd(&cur[pk & 511], 1);
        outb[pos] = pk >> 9;
    }
    __syncthreads();
    for (int i = tid; i < n; i += 256)
        col[cbase + i] = outb[i];
}

// ================= GEMM1: h1b = bf16(x @ W1)  [80000x128 @ 128x64] =================
__global__ __launch_bounds__(256) void gemm1_kernel(const float* __restrict__ x,
                                                    const float* __restrict__ W1,
                                                    unsigned* __restrict__ h1b) {
    __shared__ float w[IN_C * HID_C];     // 32 KB
    __shared__ float xt[64 * 132];        // 33.8 KB
    const int tid = threadIdx.x;

    for (int i = tid; i < IN_C * HID_C / 4; i += 256)
        ((float4*)w)[i] = ((const float4*)W1)[i];

    const int row0 = blockIdx.x * 64;
    const float4* x4 = (const float4*)(x + (size_t)row0 * IN_C);
    for (int i = tid; i < 2048; i += 256) {
        const int r = i >> 5, c = i & 31;
        *(float4*)&xt[r * 132 + c * 4] = x4[i];
    }
    __syncthreads();

    const int rg = tid >> 4;          // rows rg*4..+3
    const int cgi = tid & 15;         // cols cgi*4..+3
    float4 acc[4];
#pragma unroll
    for (int q = 0; q < 4; ++q) acc[q] = make_float4(0.f, 0.f, 0.f, 0.f);

    for (int k = 0; k < IN_C; k += 4) {
        float4 xv[4], wv[4];
#pragma unroll
        for (int q = 0; q < 4; ++q)
            xv[q] = *(const float4*)&xt[(rg * 4 + q) * 132 + k];
#pragma unroll
        for (int kk = 0; kk < 4; ++kk)
            wv[kk] = *(const float4*)&w[(k + kk) * HID_C + cgi * 4];
#pragma unroll
        for (int q = 0; q < 4; ++q) {
            acc[q].x += xv[q].x * wv[0].x + xv[q].y * wv[1].x + xv[q].z * wv[2].x + xv[q].w * wv[3].x;
            acc[q].y += xv[q].x * wv[0].y + xv[q].y * wv[1].y + xv[q].z * wv[2].y + xv[q].w * wv[3].y;
            acc[q].z += xv[q].x * wv[0].z + xv[q].y * wv[1].z + xv[q].z * wv[2].z + xv[q].w * wv[3].z;
            acc[q].w += xv[q].x * wv[0].w + xv[q].y * wv[1].w + xv[q].z * wv[2].w + xv[q].w * wv[3].w;
        }
    }
#pragma unroll
    for (int q = 0; q < 4; ++q) {
        uint2 o;
        o.x = pack_bf2(acc[q].x, acc[q].y);
        o.y = pack_bf2(acc[q].z, acc[q].w);
        // row stride = 64 ch = 32 uints; col offset cgi*4 ch = cgi*2 uints
        *(uint2*)&h1b[(size_t)(row0 + rg * 4 + q) * 32 + cgi * 2] = o;
    }
}

// ================= SpMM1 gather: 8 edges/wave, bf16 rows (128 B) =================
__global__ void gather64_kernel(const int* __restrict__ rp, const int* __restrict__ col,
                                const unsigned* __restrict__ h1b,
                                unsigned* __restrict__ agg1b) {
    const int node = blockIdx.x * 4 + (threadIdx.x >> 6);
    const int lane = threadIdx.x & 63;
    const int grp = lane >> 3;        // 8 groups of 8 lanes
    const int cg  = lane & 7;         // 8 ch (uint4) per lane
    if (node >= N_NODES) return;
    const int b = rp[node], e = rp[node + 1];
    float acc[8];
#pragma unroll
    for (int k = 0; k < 8; ++k) acc[k] = 0.f;

    for (int i = b; i < e; i += 64) {
        const int n = min(64, e - i);
        const int myIdx = (lane < n) ? col[i + lane] : 0;
        const int steps = (n + 7) >> 3;
        for (int j = 0; j < steps; ++j) {
            const int ei = (j << 3) + grp;
            const int s = __shfl(myIdx, ei, 64);
            if (ei < n) {
                const uint4 v = *(const uint4*)(h1b + (size_t)s * 32 + cg * 4);
                acc[0] += bf_lo(v.x); acc[1] += bf_hi(v.x);
                acc[2] += bf_lo(v.y); acc[3] += bf_hi(v.y);
                acc[4] += bf_lo(v.z); acc[5] += bf_hi(v.z);
                acc[6] += bf_lo(v.w); acc[7] += bf_hi(v.w);
            }
        }
    }
#pragma unroll
    for (int off = 32; off >= 8; off >>= 1)
#pragma unroll
        for (int k = 0; k < 8; ++k)
            acc[k] += __shfl_down(acc[k], off, 64);

    if (grp == 0) {
        uint4 o;
        o.x = pack_bf2(acc[0], acc[1]);
        o.y = pack_bf2(acc[2], acc[3]);
        o.z = pack_bf2(acc[4], acc[5]);
        o.w = pack_bf2(acc[6], acc[7]);
        *(uint4*)(agg1b + (size_t)node * 32 + cg * 4) = o;
    }
}

// ================= GEMM2: h2b = bf16(relu(agg1b) @ W2)  [80000x64 @ 64x40] =================
__global__ __launch_bounds__(320) void gemm2_kernel(const unsigned* __restrict__ agg1b,
                                                    const float* __restrict__ W2,
                                                    unsigned* __restrict__ h2b) {
    __shared__ float w[HID_C * OUT_C];    // 10.24 KB
    __shared__ float xt[128 * 68];        // 34.8 KB
    const int tid = threadIdx.x;

    for (int i = tid; i < HID_C * OUT_C / 4; i += 320)
        ((float4*)w)[i] = ((const float4*)W2)[i];

    const int row0 = blockIdx.x * 128;
    for (int i = tid; i < 1024; i += 320) {       // 128 rows * 8 uint4 (8 ch each)
        const int r = i >> 3, c8 = i & 7;
        const uint4 v = *(const uint4*)(agg1b + ((size_t)(row0 + r) * 32 + c8 * 4));
        float f0 = bf_lo(v.x), f1 = bf_hi(v.x), f2 = bf_lo(v.y), f3 = bf_hi(v.y);
        float f4 = bf_lo(v.z), f5 = bf_hi(v.z), f6 = bf_lo(v.w), f7 = bf_hi(v.w);
        f0 = f0 > 0.f ? f0 : 0.f; f1 = f1 > 0.f ? f1 : 0.f;
        f2 = f2 > 0.f ? f2 : 0.f; f3 = f3 > 0.f ? f3 : 0.f;
        f4 = f4 > 0.f ? f4 : 0.f; f5 = f5 > 0.f ? f5 : 0.f;
        f6 = f6 > 0.f ? f6 : 0.f; f7 = f7 > 0.f ? f7 : 0.f;
        float* p = &xt[r * 68 + c8 * 8];
        *(float4*)p = make_float4(f0, f1, f2, f3);
        *(float4*)(p + 4) = make_float4(f4, f5, f6, f7);
    }
    __syncthreads();

    const int rg = tid / 10;          // 0..31 -> rows rg*4..+3
    const int cgi = tid - rg * 10;    // 0..9  -> cols cgi*4..+3
    float4 acc[4];
#pragma unroll
    for (int q = 0; q < 4; ++q) acc[q] = make_float4(0.f, 0.f, 0.f, 0.f);

    for (int k = 0; k < HID_C; k += 4) {
        float4 xv[4], wv[4];
#pragma unroll
        for (int q = 0; q < 4; ++q)
            xv[q] = *(const float4*)&xt[(rg * 4 + q) * 68 + k];
#pragma unroll
        for (int kk = 0; kk < 4; ++kk)
            wv[kk] = *(const float4*)&w[(k + kk) * OUT_C + cgi * 4];
#pragma unroll
        for (int q = 0; q < 4; ++q) {
            acc[q].x += xv[q].x * wv[0].x + xv[q].y * wv[1].x + xv[q].z * wv[2].x + xv[q].w * wv[3].x;
            acc[q].y += xv[q].x * wv[0].y + xv[q].y * wv[1].y + xv[q].z * wv[2].y + xv[q].w * wv[3].y;
            acc[q].z += xv[q].x * wv[0].z + xv[q].y * wv[1].z + xv[q].z * wv[2].z + xv[q].w * wv[3].z;
            acc[q].w += xv[q].x * wv[0].w + xv[q].y * wv[1].w + xv[q].z * wv[2].w + xv[q].w * wv[3].w;
        }
    }
#pragma unroll
    for (int q = 0; q < 4; ++q) {
        uint2 o;
        o.x = pack_bf2(acc[q].x, acc[q].y);
        o.y = pack_bf2(acc[q].z, acc[q].w);
        // row stride = 40 ch = 20 uints; col offset cgi*4 ch = cgi*2 uints
        *(uint2*)&h2b[(size_t)(row0 + rg * 4 + q) * 20 + cgi * 2] = o;
    }
}

// ================= SpMM2 gather + log_softmax: 6 edges/wave, bf16 rows (80 B) ====
__global__ void gather40_ls_kernel(const int* __restrict__ rp, const int* __restrict__ col,
                                   const unsigned* __restrict__ h2b,
                                   float* __restrict__ out) {
    const int node = blockIdx.x * 4 + (threadIdx.x >> 6);
    const int lane = threadIdx.x & 63;
    const int grp = lane / 10;        // 6 full groups (lanes 0..59); grp6 partial idle
    const int cg  = lane - grp * 10;  // 10 lanes x 4 ch (uint2)
    if (node >= N_NODES) return;
    const bool act = lane < 60;
    const int b = rp[node], e = rp[node + 1];
    float a0 = 0.f, a1 = 0.f, a2 = 0.f, a3 = 0.f;

    for (int i = b; i < e; i += 64) {
        const int n = min(64, e - i);
        const int myIdx = (lane < n) ? col[i + lane] : 0;
        const int steps = (n + 5) / 6;
        for (int j = 0; j < steps; ++j) {
            const int ei = j * 6 + grp;
            const int s = __shfl(myIdx, ei, 64);
            if (act && ei < n) {
                const uint2 v = *(const uint2*)(h2b + (size_t)s * 20 + cg * 2);
                a0 += bf_lo(v.x); a1 += bf_hi(v.x);
                a2 += bf_lo(v.y); a3 += bf_hi(v.y);
            }
        }
    }
    // reduce 6 groups -> grp0 (lanes 0..9)
    {
        float t0 = __shfl_down(a0, 30, 64), t1 = __shfl_down(a1, 30, 64);
        float t2 = __shfl_down(a2, 30, 64), t3 = __shfl_down(a3, 30, 64);
        a0 += t0; a1 += t1; a2 += t2; a3 += t3;
        float u0 = __shfl_down(a0, 10, 64), u1 = __shfl_down(a1, 10, 64);
        float u2 = __shfl_down(a2, 10, 64), u3 = __shfl_down(a3, 10, 64);
        float w0 = __shfl_down(a0, 20, 64), w1 = __shfl_down(a1, 20, 64);
        float w2 = __shfl_down(a2, 20, 64), w3 = __shfl_down(a3, 20, 64);
        a0 += u0 + w0; a1 += u1 + w1; a2 += u2 + w2; a3 += u3 + w3;
    }

    const bool own = lane < 10;
    float vmax = own ? fmaxf(fmaxf(a0, a1), fmaxf(a2, a3)) : -INFINITY;
#pragma unroll
    for (int o = 32; o > 0; o >>= 1)
        vmax = fmaxf(vmax, __shfl_xor(vmax, o, 64));
    float s = own ? (__expf(a0 - vmax) + __expf(a1 - vmax) +
                     __expf(a2 - vmax) + __expf(a3 - vmax)) : 0.f;
#pragma unroll
    for (int o = 32; o > 0; o >>= 1)
        s += __shfl_xor(s, o, 64);
    const float ls = __logf(s) + vmax;
    if (own) {
        float4 o4 = make_float4(a0 - ls, a1 - ls, a2 - ls, a3 - ls);
        *(float4*)&out[(size_t)node * OUT_C + lane * 4] = o4;
    }
}

extern "C" void kernel_launch(void* const* d_in, const int* in_sizes, int n_in,
                              void* d_out, int out_size, void* d_ws, size_t ws_size,
                              hipStream_t stream) {
    const float* x  = (const float*)d_in[0];
    const int* eidx = (const int*)d_in[1];
    const float* W1 = (const float*)d_in[2];
    const float* W2 = (const float*)d_in[3];
    float* out = (float*)d_out;

    const int* src = eidx;             // edge_index[0]
    const int* dst = eidx + N_EDGES;   // edge_index[1]

    // Workspace (all disjoint; bf16 stored as packed uint):
    //   h1b   [80000*32 u32] 10.24 MB
    //   agg1b [80000*32 u32] 10.24 MB
    //   h2b   [80000*20 u32]  6.40 MB
    //   gbuf  [157*10240 i32] 6.43 MB
    //   col [1.28M i32], rp [80001], bcnt/bbase [157 each]
    unsigned* h1b   = (unsigned*)d_ws;
    unsigned* agg1b = h1b + (size_t)N_NODES * 32;
    unsigned* h2b   = agg1b + (size_t)N_NODES * 32;
    int*      gbuf  = (int*)(h2b + (size_t)N_NODES * 20);
    int*      col   = gbuf + (size_t)KB * BK_CAP;
    int*      rp    = col + N_EDGES;
    int*      bcnt  = rp + (N_NODES + 1);
    int*      bbase = bcnt + KB;

    // --- CSR build via binned counting sort ---
    hipMemsetAsync(bcnt, 0, KB * sizeof(int), stream);
    binA_kernel<<<(N_EDGES + 256 * EPT - 1) / (256 * EPT), 256, 0, stream>>>(src, dst, bcnt, gbuf);
    bucket_scan_kernel<<<1, 64, 0, stream>>>(bcnt, bbase);
    binB_kernel<<<KB, 256, 0, stream>>>(bcnt, bbase, gbuf, rp, col);

    // --- pipeline ---
    gemm1_kernel<<<N_NODES / 64, 256, 0, stream>>>(x, W1, h1b);
    gather64_kernel<<<(N_NODES + 3) / 4, 256, 0, stream>>>(rp, col, h1b, agg1b);
    gemm2_kernel<<<N_NODES / 128, 320, 0, stream>>>(agg1b, W2, h2b);
    gather40_ls_kernel<<<(N_NODES + 3) / 4, 256, 0, stream>>>(rp, col, h2b, out);
}

// Round 7
// 226.945 us; speedup vs baseline: 3.5279x; 1.0683x over previous
//
#include <hip/hip_runtime.h>
#include <hip/hip_bf16.h>
#include <math.h>

#define N_NODES 80000
#define N_EDGES 1280000
#define IN_C 128
#define HID_C 64
#define OUT_C 40

// Bucketed counting sort params: bucket = dst >> 9 (512 nodes per bucket)
#define KB 157            // ceil(80000 / 512)
#define BK_CAP 10240      // capacity per bucket (mean 8153 -> safe)
#define EPT 16            // edges per thread in phase A (4096 per WG)

// ---- bf16 helpers (storage bf16, math fp32) ----
__device__ __forceinline__ float bf_lo(unsigned u) {
    union { unsigned i; float f; } c; c.i = u << 16; return c.f;
}
__device__ __forceinline__ float bf_hi(unsigned u) {
    union { unsigned i; float f; } c; c.i = u & 0xffff0000u; return c.f;
}
__device__ __forceinline__ unsigned pack_bf2(float a, float b) {  // RTNE
    union { float f; unsigned i; } ca, cb; ca.f = a; cb.f = b;
    unsigned ra = (ca.i + 0x7fffu + ((ca.i >> 16) & 1u)) >> 16;
    unsigned rb = (cb.i + 0x7fffu + ((cb.i >> 16) & 1u)) >> 16;
    return ra | (rb << 16);
}

typedef short v8s __attribute__((ext_vector_type(8)));   // 8 bf16 = 4 VGPR
typedef float v4f __attribute__((ext_vector_type(4)));
union U16 { uint4 u; v8s s; };

// ================= Phase A: bin edges by dst>>9, grouped writes =================
__global__ void binA_kernel(const int* __restrict__ src, const int* __restrict__ dst,
                            int* __restrict__ bcnt, int* __restrict__ gbuf) {
    __shared__ int lcnt[KB];
    __shared__ int lexcl[KB];
    __shared__ int lbase[KB];
    __shared__ int lcur[KB];
    __shared__ int stage[256 * EPT];
    __shared__ int gaddr[256 * EPT];
    const int tid = threadIdx.x;

    for (int i = tid; i < KB; i += 256) lcnt[i] = 0;
    __syncthreads();

    const int e0 = blockIdx.x * 256 * EPT;
    int my_s[EPT], my_b[EPT], my_dl[EPT];
#pragma unroll
    for (int j = 0; j < EPT; ++j) {
        const int e = e0 + j * 256 + tid;
        if (e < N_EDGES) {
            const int d = dst[e];
            my_s[j] = src[e];
            my_b[j] = d >> 9;
            my_dl[j] = d & 511;
            atomicAdd(&lcnt[my_b[j]], 1);
        } else my_b[j] = -1;
    }
    __syncthreads();

    if (tid < KB) lexcl[tid] = lcnt[tid];
    __syncthreads();
    for (int o = 1; o < KB; o <<= 1) {
        int t = (tid < KB && tid >= o) ? lexcl[tid - o] : 0;
        __syncthreads();
        if (tid < KB) lexcl[tid] += t;
        __syncthreads();
    }
    const int total = lexcl[KB - 1];
    if (tid < KB) {
        lexcl[tid] -= lcnt[tid];
        lbase[tid] = (lcnt[tid] > 0) ? atomicAdd(&bcnt[tid], lcnt[tid]) : 0;
        lcur[tid] = 0;
    }
    __syncthreads();

#pragma unroll
    for (int j = 0; j < EPT; ++j) {
        if (my_b[j] >= 0) {
            const int b = my_b[j];
            const int r = atomicAdd(&lcur[b], 1);
            const int li = lexcl[b] + r;
            stage[li] = (my_s[j] << 9) | my_dl[j];
            int gp = lbase[b] + r;
            if (gp >= BK_CAP) gp = BK_CAP - 1;
            gaddr[li] = b * BK_CAP + gp;
        }
    }
    __syncthreads();

    for (int i = tid; i < total; i += 256)
        gbuf[gaddr[i]] = stage[i];
}

// ================= bucket base: exclusive scan of 157 counts =================
__global__ void bucket_scan_kernel(const int* __restrict__ cnt, int* __restrict__ base) {
    const int lane = threadIdx.x;
    int carry = 0;
    for (int b0 = 0; b0 < KB; b0 += 64) {
        int raw = (b0 + lane < KB) ? min(cnt[b0 + lane], BK_CAP) : 0;
        int v = raw;
        for (int o = 1; o < 64; o <<= 1) {
            int t = __shfl_up(v, o, 64);
            if (lane >= o) v += t;
        }
        if (b0 + lane < KB) base[b0 + lane] = carry + v - raw;
        carry += __shfl(v, 63, 64);
    }
}

// ================= Phase B: per-bucket -> rp + col (coalesced) =================
__global__ void binB_kernel(const int* __restrict__ bcnt, const int* __restrict__ bbase,
                            const int* __restrict__ gbuf,
                            int* __restrict__ rp, int* __restrict__ col) {
    __shared__ int hist[512];
    __shared__ int excl[512];
    __shared__ int cur[512];
    __shared__ int ps[256];
    __shared__ int outb[BK_CAP];
    const int b = blockIdx.x;
    const int tid = threadIdx.x;
    const int n = min(bcnt[b], BK_CAP);
    const int cbase = bbase[b];
    const int* __restrict__ my = gbuf + (size_t)b * BK_CAP;

    for (int i = tid; i < 512; i += 256) hist[i] = 0;
    __syncthreads();
    for (int i = tid; i < n; i += 256)
        atomicAdd(&hist[my[i] & 511], 1);
    __syncthreads();

    const int h0 = hist[2 * tid], h1 = hist[2 * tid + 1];
    const int p = h0 + h1;
    ps[tid] = p;
    __syncthreads();
    for (int o = 1; o < 256; o <<= 1) {
        int t = (tid >= o) ? ps[tid - o] : 0;
        __syncthreads();
        ps[tid] += t;
        __syncthreads();
    }
    const int pb = ps[tid] - p;
    excl[2 * tid] = pb;
    excl[2 * tid + 1] = pb + h0;
    cur[2 * tid] = pb;
    cur[2 * tid + 1] = pb + h0;
    __syncthreads();

    for (int i = tid; i < 512; i += 256) {
        const int node = b * 512 + i;
        if (node <= N_NODES) rp[node] = cbase + excl[i];
    }

    for (int i = tid; i < n; i += 256) {
        const int pk = my[i];
        const int pos = atomicAdd(&cur[pk & 511], 1);
        outb[pos] = pk >> 9;
    }
    __syncthreads();
    for (int i = tid; i < n; i += 256)
        col[cbase + i] = outb[i];
}

// ======== prep: W1^T, W2^T to bf16 (w1t[64][128], w2t[48][64] packed pairs) ========
__global__ void prep_w_kernel(const float* __restrict__ W1, const float* __restrict__ W2,
                              unsigned* __restrict__ w1t, unsigned* __restrict__ w2t) {
    const int tid = threadIdx.x;
    for (int i = tid; i < 4096; i += 256) {         // wcol*64 + kk (k pair)
        const int wcol = i >> 6, kk = i & 63;
        w1t[i] = pack_bf2(W1[(2 * kk) * HID_C + wcol], W1[(2 * kk + 1) * HID_C + wcol]);
    }
    for (int i = tid; i < 1536; i += 256) {         // wcol*32 + kk
        const int wcol = i >> 5, kk = i & 31;
        w2t[i] = (wcol < OUT_C)
            ? pack_bf2(W2[(2 * kk) * OUT_C + wcol], W2[(2 * kk + 1) * OUT_C + wcol])
            : 0u;
    }
}

// ================= GEMM1 (MFMA): h1b = bf16(x @ W1) =================
// Wave computes 16 nodes x 64 wcols. D[m=wcol][n=node]: A=W1t frags, B=x rows.
__global__ __launch_bounds__(256) void gemm1_kernel(const float* __restrict__ x,
                                                    const unsigned* __restrict__ w1t,
                                                    unsigned* __restrict__ h1b) {
    const int wave = threadIdx.x >> 6, lane = threadIdx.x & 63;
    const int nl = lane & 15, quad = lane >> 4;
    const int node = (blockIdx.x * 4 + wave) * 16 + nl;

    v4f acc[4];
#pragma unroll
    for (int q = 0; q < 4; ++q) acc[q] = (v4f){0.f, 0.f, 0.f, 0.f};

#pragma unroll
    for (int kit = 0; kit < 4; ++kit) {
        const float* xp = x + (size_t)node * IN_C + kit * 32 + quad * 8;
        const float4 lo = *(const float4*)xp;
        const float4 hi = *(const float4*)(xp + 4);
        U16 bu;
        bu.u.x = pack_bf2(lo.x, lo.y); bu.u.y = pack_bf2(lo.z, lo.w);
        bu.u.z = pack_bf2(hi.x, hi.y); bu.u.w = pack_bf2(hi.z, hi.w);
#pragma unroll
        for (int mt = 0; mt < 4; ++mt) {
            U16 au;
            au.u = *(const uint4*)(w1t + ((mt * 16 + nl) * 64 + kit * 16 + quad * 4));
            acc[mt] = __builtin_amdgcn_mfma_f32_16x16x32_bf16(au.s, bu.s, acc[mt], 0, 0, 0);
        }
    }
    // D: row(wcol within tile)=quad*4+reg, col(node)=lane&15
#pragma unroll
    for (int mt = 0; mt < 4; ++mt) {
        uint2 o;
        o.x = pack_bf2(acc[mt][0], acc[mt][1]);
        o.y = pack_bf2(acc[mt][2], acc[mt][3]);
        *(uint2*)(h1b + (size_t)node * 32 + mt * 8 + quad * 2) = o;
    }
}

// ======= SpMM1 gather: 8 edges/wave (8 grp x 8 lanes x uint4), relu on write =======
__global__ void gather64_kernel(const int* __restrict__ rp, const int* __restrict__ col,
                                const unsigned* __restrict__ h1b,
                                unsigned* __restrict__ agg1b) {
    const int node = blockIdx.x * 4 + (threadIdx.x >> 6);
    const int lane = threadIdx.x & 63;
    const int grp = lane >> 3;
    const int cg  = lane & 7;
    if (node >= N_NODES) return;
    const int b = rp[node], e = rp[node + 1];
    float acc[8];
#pragma unroll
    for (int k = 0; k < 8; ++k) acc[k] = 0.f;

    for (int i = b; i < e; i += 64) {
        const int n = min(64, e - i);
        const int myIdx = (lane < n) ? col[i + lane] : 0;
        const int steps = (n + 7) >> 3;
        int j = 0;
        for (; j + 1 < steps; j += 2) {            // 2 loads in flight
            const int e0 = (j << 3) + grp;
            const int e1 = e0 + 8;
            const int s0 = __shfl(myIdx, e0, 64);
            const int s1 = __shfl(myIdx, e1, 64);
            uint4 v0, v1; bool g0 = e0 < n, g1 = e1 < n;
            if (g0) v0 = *(const uint4*)(h1b + (size_t)s0 * 32 + cg * 4);
            if (g1) v1 = *(const uint4*)(h1b + (size_t)s1 * 32 + cg * 4);
            if (g0) {
                acc[0] += bf_lo(v0.x); acc[1] += bf_hi(v0.x);
                acc[2] += bf_lo(v0.y); acc[3] += bf_hi(v0.y);
                acc[4] += bf_lo(v0.z); acc[5] += bf_hi(v0.z);
                acc[6] += bf_lo(v0.w); acc[7] += bf_hi(v0.w);
            }
            if (g1) {
                acc[0] += bf_lo(v1.x); acc[1] += bf_hi(v1.x);
                acc[2] += bf_lo(v1.y); acc[3] += bf_hi(v1.y);
                acc[4] += bf_lo(v1.z); acc[5] += bf_hi(v1.z);
                acc[6] += bf_lo(v1.w); acc[7] += bf_hi(v1.w);
            }
        }
        if (j < steps) {
            const int ei = (j << 3) + grp;
            const int s = __shfl(myIdx, ei, 64);
            if (ei < n) {
                const uint4 v = *(const uint4*)(h1b + (size_t)s * 32 + cg * 4);
                acc[0] += bf_lo(v.x); acc[1] += bf_hi(v.x);
                acc[2] += bf_lo(v.y); acc[3] += bf_hi(v.y);
                acc[4] += bf_lo(v.z); acc[5] += bf_hi(v.z);
                acc[6] += bf_lo(v.w); acc[7] += bf_hi(v.w);
            }
        }
    }
#pragma unroll
    for (int off = 32; off >= 8; off >>= 1)
#pragma unroll
        for (int k = 0; k < 8; ++k)
            acc[k] += __shfl_down(acc[k], off, 64);

    if (grp == 0) {   // relu fused here (agg1 only feeds relu->W2)
        uint4 o;
        o.x = pack_bf2(fmaxf(acc[0], 0.f), fmaxf(acc[1], 0.f));
        o.y = pack_bf2(fmaxf(acc[2], 0.f), fmaxf(acc[3], 0.f));
        o.z = pack_bf2(fmaxf(acc[4], 0.f), fmaxf(acc[5], 0.f));
        o.w = pack_bf2(fmaxf(acc[6], 0.f), fmaxf(acc[7], 0.f));
        *(uint4*)(agg1b + (size_t)node * 32 + cg * 4) = o;
    }
}

// ================= GEMM2 (MFMA): h2b = bf16(agg1b @ W2), agg1b pre-relu'd ========
__global__ __launch_bounds__(256) void gemm2_kernel(const unsigned* __restrict__ agg1b,
                                                    const unsigned* __restrict__ w2t,
                                                    unsigned* __restrict__ h2b) {
    const int wave = threadIdx.x >> 6, lane = threadIdx.x & 63;
    const int nl = lane & 15, quad = lane >> 4;
    const int node = (blockIdx.x * 4 + wave) * 16 + nl;

    v4f acc[3];
#pragma unroll
    for (int q = 0; q < 3; ++q) acc[q] = (v4f){0.f, 0.f, 0.f, 0.f};

#pragma unroll
    for (int kit = 0; kit < 2; ++kit) {
        U16 bu;
        bu.u = *(const uint4*)(agg1b + (size_t)node * 32 + kit * 16 + quad * 4);
#pragma unroll
        for (int mt = 0; mt < 3; ++mt) {
            U16 au;
            au.u = *(const uint4*)(w2t + ((mt * 16 + nl) * 32 + kit * 16 + quad * 4));
            acc[mt] = __builtin_amdgcn_mfma_f32_16x16x32_bf16(au.s, bu.s, acc[mt], 0, 0, 0);
        }
    }
#pragma unroll
    for (int mt = 0; mt < 2; ++mt) {
        uint2 o;
        o.x = pack_bf2(acc[mt][0], acc[mt][1]);
        o.y = pack_bf2(acc[mt][2], acc[mt][3]);
        *(uint2*)(h2b + (size_t)node * 20 + mt * 8 + quad * 2) = o;
    }
    if (quad < 2) {   // wcols 32..39 only
        uint2 o;
        o.x = pack_bf2(acc[2][0], acc[2][1]);
        o.y = pack_bf2(acc[2][2], acc[2][3]);
        *(uint2*)(h2b + (size_t)node * 20 + 16 + quad * 2) = o;
    }
}

// ==== SpMM2 gather + log_softmax: 12 edges/wave (12 grp x 5 lanes x uint4) ====
__global__ void gather40_ls_kernel(const int* __restrict__ rp, const int* __restrict__ col,
                                   const unsigned* __restrict__ h2b,
                                   float* __restrict__ out) {
    const int node = blockIdx.x * 4 + (threadIdx.x >> 6);
    const int lane = threadIdx.x & 63;
    const int grp = lane / 5;         // 0..12 (grp 12 = lanes 60..63 idle)
    const int cg  = lane - grp * 5;   // 0..4, 8 ch each
    if (node >= N_NODES) return;
    const bool act = lane < 60;
    const int b = rp[node], e = rp[node + 1];
    float a[8];
#pragma unroll
    for (int k = 0; k < 8; ++k) a[k] = 0.f;

    for (int i = b; i < e; i += 64) {
        const int n = min(64, e - i);
        const int myIdx = (lane < n) ? col[i + lane] : 0;
        const int steps = (n + 11) / 12;
        int j = 0;
        for (; j + 1 < steps; j += 2) {
            const int e0 = j * 12 + grp;
            const int e1 = e0 + 12;
            const int s0 = __shfl(myIdx, e0, 64);
            const int s1 = __shfl(myIdx, e1, 64);
            uint4 v0, v1;
            const bool g0 = act && e0 < n, g1 = act && e1 < n;
            if (g0) v0 = *(const uint4*)(h2b + (size_t)s0 * 20 + cg * 4);
            if (g1) v1 = *(const uint4*)(h2b + (size_t)s1 * 20 + cg * 4);
            if (g0) {
                a[0] += bf_lo(v0.x); a[1] += bf_hi(v0.x);
                a[2] += bf_lo(v0.y); a[3] += bf_hi(v0.y);
                a[4] += bf_lo(v0.z); a[5] += bf_hi(v0.z);
                a[6] += bf_lo(v0.w); a[7] += bf_hi(v0.w);
            }
            if (g1) {
                a[0] += bf_lo(v1.x); a[1] += bf_hi(v1.x);
                a[2] += bf_lo(v1.y); a[3] += bf_hi(v1.y);
                a[4] += bf_lo(v1.z); a[5] += bf_hi(v1.z);
                a[6] += bf_lo(v1.w); a[7] += bf_hi(v1.w);
            }
        }
        if (j < steps) {
            const int ei = j * 12 + grp;
            const int s = __shfl(myIdx, ei, 64);
            if (act && ei < n) {
                const uint4 v = *(const uint4*)(h2b + (size_t)s * 20 + cg * 4);
                a[0] += bf_lo(v.x); a[1] += bf_hi(v.x);
                a[2] += bf_lo(v.y); a[3] += bf_hi(v.y);
                a[4] += bf_lo(v.z); a[5] += bf_hi(v.z);
                a[6] += bf_lo(v.w); a[7] += bf_hi(v.w);
            }
        }
    }
    // fold 12 groups of 5 lanes -> grp0 (lanes 0..4):
    //   +30: g += g+6   (groups 6..11 onto 0..5)
    //   +15: g += g+3   (groups 3..5 onto 0..2)
    //   read +5 (g1) and +10 (g2) simultaneously, then add both onto g0
#pragma unroll
    for (int k = 0; k < 8; ++k) a[k] += __shfl_down(a[k], 30, 64);
#pragma unroll
    for (int k = 0; k < 8; ++k) a[k] += __shfl_down(a[k], 15, 64);
#pragma unroll
    for (int k = 0; k < 8; ++k) {
        const float u = __shfl_down(a[k], 5, 64);
        const float w = __shfl_down(a[k], 10, 64);
        a[k] += u + w;
    }

    const bool own = lane < 5;
    float m = -INFINITY, s = 0.f;
    if (own) {
        m = a[0];
#pragma unroll
        for (int k = 1; k < 8; ++k) m = fmaxf(m, a[k]);
    }
#pragma unroll
    for (int o = 32; o > 0; o >>= 1)
        m = fmaxf(m, __shfl_xor(m, o, 64));
    if (own) {
#pragma unroll
        for (int k = 0; k < 8; ++k) s += __expf(a[k] - m);
    }
#pragma unroll
    for (int o = 32; o > 0; o >>= 1)
        s += __shfl_xor(s, o, 64);
    const float ls = __logf(s) + m;
    if (own) {
        float* op = out + (size_t)node * OUT_C + lane * 8;
        *(float4*)op = make_float4(a[0] - ls, a[1] - ls, a[2] - ls, a[3] - ls);
        *(float4*)(op + 4) = make_float4(a[4] - ls, a[5] - ls, a[6] - ls, a[7] - ls);
    }
}

extern "C" void kernel_launch(void* const* d_in, const int* in_sizes, int n_in,
                              void* d_out, int out_size, void* d_ws, size_t ws_size,
                              hipStream_t stream) {
    const float* x  = (const float*)d_in[0];
    const int* eidx = (const int*)d_in[1];
    const float* W1 = (const float*)d_in[2];
    const float* W2 = (const float*)d_in[3];
    float* out = (float*)d_out;

    const int* src = eidx;             // edge_index[0]
    const int* dst = eidx + N_EDGES;   // edge_index[1]

    // Workspace (bf16 packed as uint):
    //   h1b [80000*32], agg1b [80000*32], h2b [80000*20], gbuf [157*10240],
    //   col [1.28M], rp [80001], bcnt/bbase [157], w1t [4096], w2t [1536]
    unsigned* h1b   = (unsigned*)d_ws;
    unsigned* agg1b = h1b + (size_t)N_NODES * 32;
    unsigned* h2b   = agg1b + (size_t)N_NODES * 32;
    int*      gbuf  = (int*)(h2b + (size_t)N_NODES * 20);
    int*      col   = gbuf + (size_t)KB * BK_CAP;
    int*      rp    = col + N_EDGES;
    int*      bcnt  = rp + (N_NODES + 1);
    int*      bbase = bcnt + KB;
    unsigned* w1t   = (unsigned*)(bbase + KB);
    unsigned* w2t   = w1t + 4096;

    // --- CSR build via binned counting sort ---
    hipMemsetAsync(bcnt, 0, KB * sizeof(int), stream);
    prep_w_kernel<<<1, 256, 0, stream>>>(W1, W2, w1t, w2t);
    binA_kernel<<<(N_EDGES + 256 * EPT - 1) / (256 * EPT), 256, 0, stream>>>(src, dst, bcnt, gbuf);
    bucket_scan_kernel<<<1, 64, 0, stream>>>(bcnt, bbase);
    binB_kernel<<<KB, 256, 0, stream>>>(bcnt, bbase, gbuf, rp, col);

    // --- pipeline ---
    gemm1_kernel<<<N_NODES / 64, 256, 0, stream>>>(x, w1t, h1b);
    gather64_kernel<<<(N_NODES + 3) / 4, 256, 0, stream>>>(rp, col, h1b, agg1b);
    gemm2_kernel<<<N_NODES / 64, 256, 0, stream>>>(agg1b, w2t, h2b);
    gather40_ls_kernel<<<(N_NODES + 3) / 4, 256, 0, stream>>>(rp, col, h2b, out);
}

// Round 8
// 195.972 us; speedup vs baseline: 4.0855x; 1.1581x over previous
//
#include <hip/hip_runtime.h>
#include <hip/hip_bf16.h>
#include <math.h>

#define N_NODES 80000
#define N_EDGES 1280000
#define IN_C 128
#define HID_C 64
#define OUT_C 40

// Bucketed counting sort params: bucket = dst >> 9 (512 nodes per bucket)
#define KB 157            // ceil(80000 / 512)
#define BK_CAP 10240      // capacity per bucket (mean 8153 -> safe)
#define EPT 16            // edges per thread in phase A (4096 per WG)

// ---- bf16 helpers (storage bf16, math fp32) ----
__device__ __forceinline__ float bf_lo(unsigned u) {
    union { unsigned i; float f; } c; c.i = u << 16; return c.f;
}
__device__ __forceinline__ float bf_hi(unsigned u) {
    union { unsigned i; float f; } c; c.i = u & 0xffff0000u; return c.f;
}
__device__ __forceinline__ unsigned pack_bf2(float a, float b) {  // RTNE
    union { float f; unsigned i; } ca, cb; ca.f = a; cb.f = b;
    unsigned ra = (ca.i + 0x7fffu + ((ca.i >> 16) & 1u)) >> 16;
    unsigned rb = (cb.i + 0x7fffu + ((cb.i >> 16) & 1u)) >> 16;
    return ra | (rb << 16);
}

typedef short v8s __attribute__((ext_vector_type(8)));   // 8 bf16 = 4 VGPR
typedef float v4f __attribute__((ext_vector_type(4)));
union U16 { uint4 u; v8s s; };

// ======== prep: W1^T, W2^T to bf16 + zero bcnt ========
__global__ void prep_w_kernel(const float* __restrict__ W1, const float* __restrict__ W2,
                              unsigned* __restrict__ w1t, unsigned* __restrict__ w2t,
                              int* __restrict__ bcnt) {
    const int tid = threadIdx.x;
    if (tid < KB) bcnt[tid] = 0;
    for (int i = tid; i < 4096; i += 256) {         // wcol*64 + kk (k pair)
        const int wcol = i >> 6, kk = i & 63;
        w1t[i] = pack_bf2(W1[(2 * kk) * HID_C + wcol], W1[(2 * kk + 1) * HID_C + wcol]);
    }
    for (int i = tid; i < 1536; i += 256) {         // wcol*32 + kk
        const int wcol = i >> 5, kk = i & 31;
        w2t[i] = (wcol < OUT_C)
            ? pack_bf2(W2[(2 * kk) * OUT_C + wcol], W2[(2 * kk + 1) * OUT_C + wcol])
            : 0u;
    }
}

// ================= Phase A: bin edges by dst>>9, grouped writes =================
__global__ void binA_kernel(const int* __restrict__ src, const int* __restrict__ dst,
                            int* __restrict__ bcnt, int* __restrict__ gbuf) {
    __shared__ int lcnt[KB];
    __shared__ int lexcl[KB];
    __shared__ int lbase[KB];
    __shared__ int lcur[KB];
    __shared__ int stage[256 * EPT];
    __shared__ int gaddr[256 * EPT];
    const int tid = threadIdx.x;

    for (int i = tid; i < KB; i += 256) lcnt[i] = 0;
    __syncthreads();

    const int e0 = blockIdx.x * 256 * EPT;
    int my_s[EPT], my_b[EPT], my_dl[EPT];
#pragma unroll
    for (int j = 0; j < EPT; ++j) {
        const int e = e0 + j * 256 + tid;
        if (e < N_EDGES) {
            const int d = dst[e];
            my_s[j] = src[e];
            my_b[j] = d >> 9;
            my_dl[j] = d & 511;
            atomicAdd(&lcnt[my_b[j]], 1);
        } else my_b[j] = -1;
    }
    __syncthreads();

    if (tid < KB) lexcl[tid] = lcnt[tid];
    __syncthreads();
    for (int o = 1; o < KB; o <<= 1) {
        int t = (tid < KB && tid >= o) ? lexcl[tid - o] : 0;
        __syncthreads();
        if (tid < KB) lexcl[tid] += t;
        __syncthreads();
    }
    const int total = lexcl[KB - 1];
    if (tid < KB) {
        lexcl[tid] -= lcnt[tid];
        lbase[tid] = (lcnt[tid] > 0) ? atomicAdd(&bcnt[tid], lcnt[tid]) : 0;
        lcur[tid] = 0;
    }
    __syncthreads();

#pragma unroll
    for (int j = 0; j < EPT; ++j) {
        if (my_b[j] >= 0) {
            const int b = my_b[j];
            const int r = atomicAdd(&lcur[b], 1);
            const int li = lexcl[b] + r;
            stage[li] = (my_s[j] << 9) | my_dl[j];
            int gp = lbase[b] + r;
            if (gp >= BK_CAP) gp = BK_CAP - 1;
            gaddr[li] = b * BK_CAP + gp;
        }
    }
    __syncthreads();

    for (int i = tid; i < total; i += 256)
        gbuf[gaddr[i]] = stage[i];
}

// ===== Phase B: per-bucket -> rp + col (coalesced); bucket bases scanned in-block =====
__global__ void binB_kernel(const int* __restrict__ bcnt,
                            const int* __restrict__ gbuf,
                            int* __restrict__ rp, int* __restrict__ col) {
    __shared__ int sc[KB];
    __shared__ int hist[512];
    __shared__ int excl[512];
    __shared__ int cur[512];
    __shared__ int ps[256];
    __shared__ int outb[BK_CAP];
    const int b = blockIdx.x;
    const int tid = threadIdx.x;

    // inclusive scan of clamped bucket counts (KB=157)
    if (tid < KB) sc[tid] = min(bcnt[tid], BK_CAP);
    __syncthreads();
    for (int o = 1; o < KB; o <<= 1) {
        int t = (tid < KB && tid >= o) ? sc[tid - o] : 0;
        __syncthreads();
        if (tid < KB) sc[tid] += t;
        __syncthreads();
    }
    const int n = min(bcnt[b], BK_CAP);
    const int cbase = sc[b] - n;
    const int* __restrict__ my = gbuf + (size_t)b * BK_CAP;

    for (int i = tid; i < 512; i += 256) hist[i] = 0;
    __syncthreads();
    for (int i = tid; i < n; i += 256)
        atomicAdd(&hist[my[i] & 511], 1);
    __syncthreads();

    const int h0 = hist[2 * tid], h1 = hist[2 * tid + 1];
    const int p = h0 + h1;
    ps[tid] = p;
    __syncthreads();
    for (int o = 1; o < 256; o <<= 1) {
        int t = (tid >= o) ? ps[tid - o] : 0;
        __syncthreads();
        ps[tid] += t;
        __syncthreads();
    }
    const int pb = ps[tid] - p;
    excl[2 * tid] = pb;
    excl[2 * tid + 1] = pb + h0;
    cur[2 * tid] = pb;
    cur[2 * tid + 1] = pb + h0;
    __syncthreads();

    for (int i = tid; i < 512; i += 256) {
        const int node = b * 512 + i;
        if (node <= N_NODES) rp[node] = cbase + excl[i];
    }

    for (int i = tid; i < n; i += 256) {
        const int pk = my[i];
        const int pos = atomicAdd(&cur[pk & 511], 1);
        outb[pos] = pk >> 9;
    }
    __syncthreads();
    for (int i = tid; i < n; i += 256)
        col[cbase + i] = outb[i];
}

// ================= GEMM1 (MFMA): h1b = bf16(x @ W1) =================
__global__ __launch_bounds__(256) void gemm1_kernel(const float* __restrict__ x,
                                                    const unsigned* __restrict__ w1t,
                                                    unsigned* __restrict__ h1b) {
    const int wave = threadIdx.x >> 6, lane = threadIdx.x & 63;
    const int nl = lane & 15, quad = lane >> 4;
    const int node = (blockIdx.x * 4 + wave) * 16 + nl;

    v4f acc[4];
#pragma unroll
    for (int q = 0; q < 4; ++q) acc[q] = (v4f){0.f, 0.f, 0.f, 0.f};

#pragma unroll
    for (int kit = 0; kit < 4; ++kit) {
        const float* xp = x + (size_t)node * IN_C + kit * 32 + quad * 8;
        const float4 lo = *(const float4*)xp;
        const float4 hi = *(const float4*)(xp + 4);
        U16 bu;
        bu.u.x = pack_bf2(lo.x, lo.y); bu.u.y = pack_bf2(lo.z, lo.w);
        bu.u.z = pack_bf2(hi.x, hi.y); bu.u.w = pack_bf2(hi.z, hi.w);
#pragma unroll
        for (int mt = 0; mt < 4; ++mt) {
            U16 au;
            au.u = *(const uint4*)(w1t + ((mt * 16 + nl) * 64 + kit * 16 + quad * 4));
            acc[mt] = __builtin_amdgcn_mfma_f32_16x16x32_bf16(au.s, bu.s, acc[mt], 0, 0, 0);
        }
    }
#pragma unroll
    for (int mt = 0; mt < 4; ++mt) {
        uint2 o;
        o.x = pack_bf2(acc[mt][0], acc[mt][1]);
        o.y = pack_bf2(acc[mt][2], acc[mt][3]);
        *(uint2*)(h1b + (size_t)node * 32 + mt * 8 + quad * 2) = o;
    }
}

// ===== SpMM1 gather: 2 nodes/wave (32 lanes = 4 edges x 8 lanes x uint4), relu =====
__global__ void gather64_kernel(const int* __restrict__ rp, const int* __restrict__ col,
                                const unsigned* __restrict__ h1b,
                                unsigned* __restrict__ agg1b) {
    const int lane = threadIdx.x & 63;
    const int wave = threadIdx.x >> 6;
    const int sl = lane & 31;          // sub-lane within node group
    const int es = sl >> 3;            // edge slot 0..3
    const int cl = sl & 7;             // channel group (uint4 = 8 ch)
    const int gbase = lane & 32;       // group base lane
    const int node = blockIdx.x * 8 + wave * 2 + (lane >> 5);
    const int b = rp[node], e = rp[node + 1];

    float acc[8];
#pragma unroll
    for (int k = 0; k < 8; ++k) acc[k] = 0.f;

    for (int pos = b; __any(pos < e); pos += 32) {
        const int rem = e - pos;
        const int n = rem > 32 ? 32 : (rem > 0 ? rem : 0);
        const int myIdx = (sl < n) ? col[pos + sl] : 0;
        const int steps = (n + 3) >> 2;
        int j = 0;
        for (; j + 1 < steps; j += 2) {
            const int e0 = (j << 2) + es, e1 = e0 + 4;
            const int s0 = __shfl(myIdx, gbase + e0, 64);
            const int s1 = __shfl(myIdx, gbase + e1, 64);
            uint4 v0, v1;
            const bool g0 = e0 < n, g1 = e1 < n;
            if (g0) v0 = *(const uint4*)(h1b + (size_t)s0 * 32 + cl * 4);
            if (g1) v1 = *(const uint4*)(h1b + (size_t)s1 * 32 + cl * 4);
            if (g0) {
                acc[0] += bf_lo(v0.x); acc[1] += bf_hi(v0.x);
                acc[2] += bf_lo(v0.y); acc[3] += bf_hi(v0.y);
                acc[4] += bf_lo(v0.z); acc[5] += bf_hi(v0.z);
                acc[6] += bf_lo(v0.w); acc[7] += bf_hi(v0.w);
            }
            if (g1) {
                acc[0] += bf_lo(v1.x); acc[1] += bf_hi(v1.x);
                acc[2] += bf_lo(v1.y); acc[3] += bf_hi(v1.y);
                acc[4] += bf_lo(v1.z); acc[5] += bf_hi(v1.z);
                acc[6] += bf_lo(v1.w); acc[7] += bf_hi(v1.w);
            }
        }
        if (j < steps) {
            const int e0 = (j << 2) + es;
            const int s0 = __shfl(myIdx, gbase + e0, 64);
            if (e0 < n) {
                const uint4 v = *(const uint4*)(h1b + (size_t)s0 * 32 + cl * 4);
                acc[0] += bf_lo(v.x); acc[1] += bf_hi(v.x);
                acc[2] += bf_lo(v.y); acc[3] += bf_hi(v.y);
                acc[4] += bf_lo(v.z); acc[5] += bf_hi(v.z);
                acc[6] += bf_lo(v.w); acc[7] += bf_hi(v.w);
            }
        }
    }
    // fold 4 edge-slots -> slot 0 (lanes sl<8), within each 32-lane group
#pragma unroll
    for (int k = 0; k < 8; ++k) acc[k] += __shfl_down(acc[k], 16, 64);
#pragma unroll
    for (int k = 0; k < 8; ++k) acc[k] += __shfl_down(acc[k], 8, 64);

    if (sl < 8) {   // relu fused (agg1 only feeds relu->W2)
        uint4 o;
        o.x = pack_bf2(fmaxf(acc[0], 0.f), fmaxf(acc[1], 0.f));
        o.y = pack_bf2(fmaxf(acc[2], 0.f), fmaxf(acc[3], 0.f));
        o.z = pack_bf2(fmaxf(acc[4], 0.f), fmaxf(acc[5], 0.f));
        o.w = pack_bf2(fmaxf(acc[6], 0.f), fmaxf(acc[7], 0.f));
        *(uint4*)(agg1b + (size_t)node * 32 + cl * 4) = o;
    }
}

// ================= GEMM2 (MFMA): h2b = bf16(agg1b @ W2), agg1b pre-relu'd ========
__global__ __launch_bounds__(256) void gemm2_kernel(const unsigned* __restrict__ agg1b,
                                                    const unsigned* __restrict__ w2t,
                                                    unsigned* __restrict__ h2b) {
    const int wave = threadIdx.x >> 6, lane = threadIdx.x & 63;
    const int nl = lane & 15, quad = lane >> 4;
    const int node = (blockIdx.x * 4 + wave) * 16 + nl;

    v4f acc[3];
#pragma unroll
    for (int q = 0; q < 3; ++q) acc[q] = (v4f){0.f, 0.f, 0.f, 0.f};

#pragma unroll
    for (int kit = 0; kit < 2; ++kit) {
        U16 bu;
        bu.u = *(const uint4*)(agg1b + (size_t)node * 32 + kit * 16 + quad * 4);
#pragma unroll
        for (int mt = 0; mt < 3; ++mt) {
            U16 au;
            au.u = *(const uint4*)(w2t + ((mt * 16 + nl) * 32 + kit * 16 + quad * 4));
            acc[mt] = __builtin_amdgcn_mfma_f32_16x16x32_bf16(au.s, bu.s, acc[mt], 0, 0, 0);
        }
    }
#pragma unroll
    for (int mt = 0; mt < 2; ++mt) {
        uint2 o;
        o.x = pack_bf2(acc[mt][0], acc[mt][1]);
        o.y = pack_bf2(acc[mt][2], acc[mt][3]);
        *(uint2*)(h2b + (size_t)node * 20 + mt * 8 + quad * 2) = o;
    }
    if (quad < 2) {   // wcols 32..39
        uint2 o;
        o.x = pack_bf2(acc[2][0], acc[2][1]);
        o.y = pack_bf2(acc[2][2], acc[2][3]);
        *(uint2*)(h2b + (size_t)node * 20 + 16 + quad * 2) = o;
    }
}

// ==== SpMM2 gather + log_softmax: 4 nodes/wave (16 lanes = 3 edges x 5 x uint4) ====
__global__ void gather40_ls_kernel(const int* __restrict__ rp, const int* __restrict__ col,
                                   const unsigned* __restrict__ h2b,
                                   float* __restrict__ out) {
    const int lane = threadIdx.x & 63;
    const int wave = threadIdx.x >> 6;
    const int sl = lane & 15;
    const int es = sl / 5;            // 0..3 (es==3: lane 15 idle for loads)
    const int cl = sl - es * 5;       // 0..4 (uint4 = 8 ch each)
    const int gbase = lane & 48;      // group base lane (g*16)
    const int node = blockIdx.x * 16 + wave * 4 + (lane >> 4);
    const int b = rp[node], e = rp[node + 1];

    float a[8];
#pragma unroll
    for (int k = 0; k < 8; ++k) a[k] = 0.f;

    for (int pos = b; __any(pos < e); pos += 16) {
        const int rem = e - pos;
        const int n = rem > 16 ? 16 : (rem > 0 ? rem : 0);
        const int myIdx = (sl < n) ? col[pos + sl] : 0;
        const int steps = (n + 2) / 3;
        int j = 0;
        for (; j + 1 < steps; j += 2) {
            const int e0 = j * 3 + es, e1 = e0 + 3;
            const int s0 = __shfl(myIdx, gbase + e0, 64);
            const int s1 = __shfl(myIdx, gbase + e1, 64);
            uint4 v0, v1;
            const bool g0 = (es < 3) && (e0 < n), g1 = (es < 3) && (e1 < n);
            if (g0) v0 = *(const uint4*)(h2b + (size_t)s0 * 20 + cl * 4);
            if (g1) v1 = *(const uint4*)(h2b + (size_t)s1 * 20 + cl * 4);
            if (g0) {
                a[0] += bf_lo(v0.x); a[1] += bf_hi(v0.x);
                a[2] += bf_lo(v0.y); a[3] += bf_hi(v0.y);
                a[4] += bf_lo(v0.z); a[5] += bf_hi(v0.z);
                a[6] += bf_lo(v0.w); a[7] += bf_hi(v0.w);
            }
            if (g1) {
                a[0] += bf_lo(v1.x); a[1] += bf_hi(v1.x);
                a[2] += bf_lo(v1.y); a[3] += bf_hi(v1.y);
                a[4] += bf_lo(v1.z); a[5] += bf_hi(v1.z);
                a[6] += bf_lo(v1.w); a[7] += bf_hi(v1.w);
            }
        }
        if (j < steps) {
            const int e0 = j * 3 + es;
            const int s0 = __shfl(myIdx, gbase + e0, 64);
            if ((es < 3) && (e0 < n)) {
                const uint4 v = *(const uint4*)(h2b + (size_t)s0 * 20 + cl * 4);
                a[0] += bf_lo(v.x); a[1] += bf_hi(v.x);
                a[2] += bf_lo(v.y); a[3] += bf_hi(v.y);
                a[4] += bf_lo(v.z); a[5] += bf_hi(v.z);
                a[6] += bf_lo(v.w); a[7] += bf_hi(v.w);
            }
        }
    }
    // fold 3 edge-slots -> lanes sl<5 within each 16-lane group
#pragma unroll
    for (int k = 0; k < 8; ++k) {
        const float u = __shfl_down(a[k], 5, 64);
        const float w = __shfl_down(a[k], 10, 64);
        a[k] += u + w;
    }

    const bool own = sl < 5;
    float m = -INFINITY;
    if (own) {
        m = a[0];
#pragma unroll
        for (int k = 1; k < 8; ++k) m = fmaxf(m, a[k]);
    }
    // group max across the 5 owner lanes (broadcast to whole group)
    const float m0 = __shfl(m, gbase + 0, 64), m1 = __shfl(m, gbase + 1, 64);
    const float m2 = __shfl(m, gbase + 2, 64), m3 = __shfl(m, gbase + 3, 64);
    const float m4 = __shfl(m, gbase + 4, 64);
    const float gm = fmaxf(fmaxf(fmaxf(m0, m1), fmaxf(m2, m3)), m4);

    float s = 0.f;
    if (own) {
#pragma unroll
        for (int k = 0; k < 8; ++k) s += __expf(a[k] - gm);
    }
    const float s0 = __shfl(s, gbase + 0, 64), s1 = __shfl(s, gbase + 1, 64);
    const float s2 = __shfl(s, gbase + 2, 64), s3 = __shfl(s, gbase + 3, 64);
    const float s4 = __shfl(s, gbase + 4, 64);
    const float ls = __logf(s0 + s1 + s2 + s3 + s4) + gm;

    if (own) {
        float* op = out + (size_t)node * OUT_C + cl * 8;
        *(float4*)op = make_float4(a[0] - ls, a[1] - ls, a[2] - ls, a[3] - ls);
        *(float4*)(op + 4) = make_float4(a[4] - ls, a[5] - ls, a[6] - ls, a[7] - ls);
    }
}

extern "C" void kernel_launch(void* const* d_in, const int* in_sizes, int n_in,
                              void* d_out, int out_size, void* d_ws, size_t ws_size,
                              hipStream_t stream) {
    const float* x  = (const float*)d_in[0];
    const int* eidx = (const int*)d_in[1];
    const float* W1 = (const float*)d_in[2];
    const float* W2 = (const float*)d_in[3];
    float* out = (float*)d_out;

    const int* src = eidx;             // edge_index[0]
    const int* dst = eidx + N_EDGES;   // edge_index[1]

    // Workspace (bf16 packed as uint):
    //   h1b [80000*32], agg1b [80000*32], h2b [80000*20], gbuf [157*10240],
    //   col [1.28M], rp [80001], bcnt [157], w1t [4096], w2t [1536]
    unsigned* h1b   = (unsigned*)d_ws;
    unsigned* agg1b = h1b + (size_t)N_NODES * 32;
    unsigned* h2b   = agg1b + (size_t)N_NODES * 32;
    int*      gbuf  = (int*)(h2b + (size_t)N_NODES * 20);
    int*      col   = gbuf + (size_t)KB * BK_CAP;
    int*      rp    = col + N_EDGES;
    int*      bcnt  = rp + (N_NODES + 1);
    unsigned* w1t   = (unsigned*)(bcnt + KB);
    unsigned* w2t   = w1t + 4096;

    // --- prep (weights->bf16, zero bcnt) + CSR build via binned counting sort ---
    prep_w_kernel<<<1, 256, 0, stream>>>(W1, W2, w1t, w2t, bcnt);
    binA_kernel<<<(N_EDGES + 256 * EPT - 1) / (256 * EPT), 256, 0, stream>>>(src, dst, bcnt, gbuf);
    binB_kernel<<<KB, 256, 0, stream>>>(bcnt, gbuf, rp, col);

    // --- pipeline ---
    gemm1_kernel<<<N_NODES / 64, 256, 0, stream>>>(x, w1t, h1b);
    gather64_kernel<<<N_NODES / 8, 256, 0, stream>>>(rp, col, h1b, agg1b);
    gemm2_kernel<<<N_NODES / 64, 256, 0, stream>>>(agg1b, w2t, h2b);
    gather40_ls_kernel<<<N_NODES / 16, 256, 0, stream>>>(rp, col, h2b, out);
}